// Round 3
// baseline (21098.013 us; speedup 1.0000x reference)
//
#include <hip/hip_runtime.h>
#include <hip/hip_bf16.h>
#include <float.h>

#define NPTS 16384
#define KK 20
#define COUT 3

typedef float f4 __attribute__((ext_vector_type(4)));

// ---------------- top-k insert (static-indexed, stays in VGPRs) ----------------
__device__ __forceinline__ void topk_insert(float (&td)[KK], int (&tix)[KK],
                                            float &kmax, float nd, int ni) {
  float cd = nd; int ci = ni;
#pragma unroll
  for (int j = 0; j < KK; ++j) {
    if (cd < td[j]) {
      float t0 = td[j]; int t1 = tix[j];
      td[j] = cd; tix[j] = ci;
      cd = t0; ci = t1;
    }
  }
  kmax = td[KK - 1];
}

// ---------------- row squared norms ----------------
template<int C>
__global__ void norms_kernel(const float* __restrict__ X, int ldx, float* __restrict__ vn) {
  int i = blockIdx.x * 256 + threadIdx.x;
  if (i >= NPTS) return;
  const float* row = X + (size_t)i * ldx;
  float s = 0.f;
#pragma unroll
  for (int c = 0; c < C; ++c) s = fmaf(row[c], row[c], s);
  vn[i] = s;
}

// ---------------- knn: per-block 128 queries x (NPTS/4) candidates ----------------
// grid (128, 4), block 256. K-dim chunked by 32. Static LDS = 49.4 KB (< 64 KB).
// Writes per-(query, half) sorted top-20 partial lists: layout [4][NPTS][2][20].
template<int C>
__global__ __launch_bounds__(256, 2)
void knn_kernel(const float* __restrict__ X, int ldx, const float* __restrict__ vn,
                float* __restrict__ pd, int* __restrict__ pi) {
  constexpr int QT = 128, CT = 128, CSTR = CT + 4;
  constexpr int KC = (C < 32) ? C : 32;
  constexpr int NCH = (C + KC - 1) / KC;
  __shared__ __align__(16) float Qs[KC * QT];     // dim-major query slice
  __shared__ __align__(16) float Cs[KC * CSTR];   // dim-major candidate slice
  __shared__ float cnorm[CT];
  __shared__ __align__(16) float Dt[QT * 32];     // swizzled 32-col distance chunk

  const int t = threadIdx.x;
  const int qb = blockIdx.x * QT;
  const int csplit = blockIdx.y;
  const int cbase = csplit * (NPTS / 4);

  const int tq = t & 15, tc = t >> 4;
  const int q0 = tq * 8, c0 = tc * 8;
  const int mych = tc >> 2;          // which 32-col chunk this thread writes
  const int cl0 = (tc & 3) * 8;      // chunk-local col group
  const int sq = t >> 1;             // scan row (0..127)
  const int sj0 = (t & 1) * 16;      // scan col half within chunk
  const int swq = (((sq >> 3) ^ sq) & 7) << 2;

  float tkd[KK]; int tki[KK];
#pragma unroll
  for (int j = 0; j < KK; ++j) { tkd[j] = FLT_MAX; tki[j] = 0; }
  float kmax = FLT_MAX;

  for (int ct = 0; ct < (NPTS / 4) / CT; ++ct) {
    const int cb = cbase + ct * CT;

    float acc[8][8];
#pragma unroll
    for (int i = 0; i < 8; ++i)
#pragma unroll
      for (int j = 0; j < 8; ++j) acc[i][j] = 0.f;

    for (int kc = 0; kc < NCH; ++kc) {
      __syncthreads();  // prior scans / prior-chunk compute done; safe to overwrite tiles
      for (int idx = t; idx < KC * QT; idx += 256) {
        int q = idx / KC, c = idx - q * KC;
        Qs[c * QT + q] = X[(size_t)(qb + q) * ldx + kc * KC + c];
      }
      for (int idx = t; idx < KC * CT; idx += 256) {
        int j = idx / KC, c = idx - j * KC;
        Cs[c * CSTR + j] = X[(size_t)(cb + j) * ldx + kc * KC + c];
      }
      if (kc == 0 && t < CT) cnorm[t] = vn[cb + t];
      __syncthreads();

#pragma unroll 2
      for (int d = 0; d < KC; ++d) {
        f4 qa = *(const f4*)&Qs[d * QT + q0];
        f4 qbv = *(const f4*)&Qs[d * QT + q0 + 4];
        f4 ca = *(const f4*)&Cs[d * CSTR + c0];
        f4 cbv = *(const f4*)&Cs[d * CSTR + c0 + 4];
        float qr[8] = {qa[0], qa[1], qa[2], qa[3], qbv[0], qbv[1], qbv[2], qbv[3]};
        float cr[8] = {ca[0], ca[1], ca[2], ca[3], cbv[0], cbv[1], cbv[2], cbv[3]};
#pragma unroll
        for (int i = 0; i < 8; ++i)
#pragma unroll
          for (int j = 0; j < 8; ++j)
            acc[i][j] = fmaf(qr[i], cr[j], acc[i][j]);
      }
    }

    // s = |xj|^2 - 2<xi,xj>  (|xi|^2 is a per-query constant; ordering unchanged)
#pragma unroll
    for (int j = 0; j < 8; ++j) {
      float cv = cnorm[c0 + j];
#pragma unroll
      for (int i = 0; i < 8; ++i)
        acc[i][j] = fmaf(-2.f, acc[i][j], cv);
    }

    for (int ch = 0; ch < 4; ++ch) {
      __syncthreads();  // previous chunk scan done
      if (mych == ch) {
#pragma unroll
        for (int i = 0; i < 8; ++i) {
          int qq = q0 + i;
          int sw = (((qq >> 3) ^ qq) & 7) << 2;
          f4 v0 = {acc[i][0], acc[i][1], acc[i][2], acc[i][3]};
          f4 v1 = {acc[i][4], acc[i][5], acc[i][6], acc[i][7]};
          *(f4*)&Dt[qq * 32 + (cl0 ^ sw)] = v0;
          *(f4*)&Dt[qq * 32 + ((cl0 + 4) ^ sw)] = v1;
        }
      }
      __syncthreads();
      int cind0 = cb + ch * 32 + sj0;
#pragma unroll
      for (int u = 0; u < 4; ++u) {
        f4 dv = *(const f4*)&Dt[sq * 32 + ((sj0 + u * 4) ^ swq)];
#pragma unroll
        for (int e = 0; e < 4; ++e) {
          float dval = dv[e];
          if (dval < kmax) topk_insert(tkd, tki, kmax, dval, cind0 + u * 4 + e);
        }
      }
    }
  }

  // partial list layout: [4 csplit][NPTS][2 half][20]
  size_t off = (((size_t)csplit * NPTS + (qb + sq)) * 2 + (t & 1)) * KK;
#pragma unroll
  for (int j = 0; j < KK; ++j) { pd[off + j] = tkd[j]; pi[off + j] = tki[j]; }
}

// ---------------- merge 8 sorted partial lists -> final top-20 ----------------
__global__ void knn_merge_kernel(const float* __restrict__ pd, const int* __restrict__ pi,
                                 int* __restrict__ ind) {
  int q = blockIdx.x * 256 + threadIdx.x;
  float tkd[KK]; int tki[KK];
#pragma unroll
  for (int j = 0; j < KK; ++j) { tkd[j] = FLT_MAX; tki[j] = 0; }
  float kmax = FLT_MAX;
  for (int s = 0; s < 8; ++s) {
    size_t off = (((size_t)(s >> 1) * NPTS + q) * 2 + (s & 1)) * KK;
    for (int j = 0; j < KK; ++j) {
      float d = pd[off + j];
      if (d < kmax) topk_insert(tkd, tki, kmax, d, pi[off + j]);
      else break;  // lists are sorted ascending
    }
  }
#pragma unroll
  for (int j = 0; j < KK; ++j) ind[q * KK + j] = tki[j];
}

// ---------------- edge conv: gather + (f@W1 prelu [@W2 prelu]) + max over k ----------
// W1/W2 read directly from global (L1/L2-resident, coalesced). LDS <= 62.8 KB.
template<int CIN, bool TWO>
__global__ __launch_bounds__(256, 2)
void edgeconv_kernel(const float* __restrict__ X, int ldx,
                     const int* __restrict__ ind,
                     const float* __restrict__ W1, const float* __restrict__ p1p,
                     const float* __restrict__ W2, const float* __restrict__ p2p,
                     float* __restrict__ Y, int ldy) {
  constexpr int F = 2 * CIN;
  __shared__ __align__(16) float ft[4][F * KK];
  __shared__ __align__(16) float h1t[4][TWO ? 64 * KK : 4];
  __shared__ float xis[4][CIN];
  __shared__ int nbs[4][KK];

  const int t = threadIdx.x;
  const int w = t >> 6, l = t & 63;
  const float a1 = *p1p;
  float a2 = 0.f;
  if constexpr (TWO) a2 = *p2p;

  for (int pp = 0; pp < 8; ++pp) {
    const int i = blockIdx.x * 32 + w * 8 + pp;
    __syncthreads();  // previous iteration's reads of ft/h1t/xis/nbs done
    if (l < CIN) xis[w][l] = X[(size_t)i * ldx + l];
    if (l < KK) nbs[w][l] = ind[i * KK + l];
    __syncthreads();
    // build f = [xj - xi, xi], layout ft[j*20 + k]
    for (int idx = l; idx < F * KK; idx += 64) {
      int j = idx / KK, k = idx - j * KK;
      float v;
      if (j < CIN) v = X[(size_t)nbs[w][k] * ldx + j] - xis[w][j];
      else v = xis[w][j - CIN];
      ft[w][idx] = v;
    }
    __syncthreads();

    if constexpr (TWO) {
#pragma unroll
      for (int kb = 0; kb < KK; kb += 4) {
        float s0 = 0.f, s1 = 0.f, s2 = 0.f, s3 = 0.f;
#pragma unroll 4
        for (int j = 0; j < F; ++j) {
          f4 fv = *(const f4*)&ft[w][j * KK + kb];
          float wv = W1[j * 64 + l];
          s0 = fmaf(fv[0], wv, s0);
          s1 = fmaf(fv[1], wv, s1);
          s2 = fmaf(fv[2], wv, s2);
          s3 = fmaf(fv[3], wv, s3);
        }
        f4 h;
        h[0] = fmaxf(s0, 0.f) + a1 * fminf(s0, 0.f);
        h[1] = fmaxf(s1, 0.f) + a1 * fminf(s1, 0.f);
        h[2] = fmaxf(s2, 0.f) + a1 * fminf(s2, 0.f);
        h[3] = fmaxf(s3, 0.f) + a1 * fminf(s3, 0.f);
        *(f4*)&h1t[w][l * KK + kb] = h;
      }
      __syncthreads();
      float mx = -FLT_MAX;
#pragma unroll
      for (int kb = 0; kb < KK; kb += 4) {
        float s0 = 0.f, s1 = 0.f, s2 = 0.f, s3 = 0.f;
#pragma unroll 4
        for (int j = 0; j < 64; ++j) {
          f4 hv = *(const f4*)&h1t[w][j * KK + kb];
          float wv = W2[j * 64 + l];
          s0 = fmaf(hv[0], wv, s0);
          s1 = fmaf(hv[1], wv, s1);
          s2 = fmaf(hv[2], wv, s2);
          s3 = fmaf(hv[3], wv, s3);
        }
        float v0 = fmaxf(s0, 0.f) + a2 * fminf(s0, 0.f);
        float v1 = fmaxf(s1, 0.f) + a2 * fminf(s1, 0.f);
        float v2 = fmaxf(s2, 0.f) + a2 * fminf(s2, 0.f);
        float v3 = fmaxf(s3, 0.f) + a2 * fminf(s3, 0.f);
        mx = fmaxf(mx, fmaxf(fmaxf(v0, v1), fmaxf(v2, v3)));
      }
      Y[(size_t)i * ldy + l] = mx;
    } else {
      float mx = -FLT_MAX;
#pragma unroll
      for (int kb = 0; kb < KK; kb += 4) {
        float s0 = 0.f, s1 = 0.f, s2 = 0.f, s3 = 0.f;
#pragma unroll 4
        for (int j = 0; j < F; ++j) {
          f4 fv = *(const f4*)&ft[w][j * KK + kb];
          float wv = W1[j * 64 + l];
          s0 = fmaf(fv[0], wv, s0);
          s1 = fmaf(fv[1], wv, s1);
          s2 = fmaf(fv[2], wv, s2);
          s3 = fmaf(fv[3], wv, s3);
        }
        float v0 = fmaxf(s0, 0.f) + a1 * fminf(s0, 0.f);
        float v1 = fmaxf(s1, 0.f) + a1 * fminf(s1, 0.f);
        float v2 = fmaxf(s2, 0.f) + a1 * fminf(s2, 0.f);
        float v3 = fmaxf(s3, 0.f) + a1 * fminf(s3, 0.f);
        mx = fmaxf(mx, fmaxf(fmaxf(v0, v1), fmaxf(v2, v3)));
      }
      Y[(size_t)i * ldy + l] = mx;
    }
  }
}

// ---------------- ordered-float encode for atomicMax ----------------
__device__ __forceinline__ unsigned fenc(float f) {
  unsigned u = __float_as_uint(f);
  return (u & 0x80000000u) ? ~u : (u | 0x80000000u);
}
__device__ __forceinline__ float fdec(unsigned u) {
  return (u & 0x80000000u) ? __uint_as_float(u & 0x7fffffffu) : __uint_as_float(~u);
}

__global__ void initg_kernel(unsigned* __restrict__ g) {
  g[blockIdx.x * 256 + threadIdx.x] = 0x007FFFFFu;  // fenc(-inf)
}

// ---------------- generic fp32 GEMM + prelu; MODE: 0 store, 1 colmax, 2 bias+store ----
template<int MODE>
__global__ __launch_bounds__(256, 2)
void gemm_kernel(const float* __restrict__ A, int lda,
                 const float* __restrict__ W, int ldw,
                 const float* __restrict__ bias,
                 const float* __restrict__ pptr,
                 float* __restrict__ Cm, int ldc, int Ktot,
                 unsigned* __restrict__ gmax) {
  __shared__ __align__(16) float At[16 * 132];
  __shared__ __align__(16) float Ws[16 * 128];
  const int t = threadIdx.x;
  const int rb = blockIdx.x * 128, cbb = blockIdx.y * 128;
  const int r0 = (t & 15) * 8, c0 = (t >> 4) * 8;
  const float aa = *pptr;

  float acc[8][8];
#pragma unroll
  for (int i = 0; i < 8; ++i)
#pragma unroll
    for (int j = 0; j < 8; ++j) acc[i][j] = 0.f;

  const int sr = t >> 1, skh = (t & 1) * 8;
  const int wk = t >> 4, wc = (t & 15) * 8;

  for (int k0 = 0; k0 < Ktot; k0 += 16) {
    __syncthreads();
    {
      const float* ap = &A[(size_t)(rb + sr) * lda + k0 + skh];
      f4 v0 = *(const f4*)ap;
      f4 v1 = *(const f4*)(ap + 4);
#pragma unroll
      for (int e = 0; e < 4; ++e) {
        At[(skh + e) * 132 + sr] = v0[e];
        At[(skh + 4 + e) * 132 + sr] = v1[e];
      }
      const float* wp = &W[(size_t)(k0 + wk) * ldw + cbb + wc];
      *(f4*)&Ws[wk * 128 + wc] = *(const f4*)wp;
      *(f4*)&Ws[wk * 128 + wc + 4] = *(const f4*)(wp + 4);
    }
    __syncthreads();
#pragma unroll 4
    for (int d = 0; d < 16; ++d) {
      f4 qa = *(const f4*)&At[d * 132 + r0];
      f4 qb = *(const f4*)&At[d * 132 + r0 + 4];
      f4 wa = *(const f4*)&Ws[d * 128 + c0];
      f4 wb = *(const f4*)&Ws[d * 128 + c0 + 4];
      float qr[8] = {qa[0], qa[1], qa[2], qa[3], qb[0], qb[1], qb[2], qb[3]};
      float wr[8] = {wa[0], wa[1], wa[2], wa[3], wb[0], wb[1], wb[2], wb[3]};
#pragma unroll
      for (int i = 0; i < 8; ++i)
#pragma unroll
        for (int j = 0; j < 8; ++j)
          acc[i][j] = fmaf(qr[i], wr[j], acc[i][j]);
    }
  }

  float bv[8];
#pragma unroll
  for (int j = 0; j < 8; ++j) bv[j] = (MODE == 2) ? bias[cbb + c0 + j] : 0.f;
#pragma unroll
  for (int i = 0; i < 8; ++i)
#pragma unroll
    for (int j = 0; j < 8; ++j) {
      float v = acc[i][j] + bv[j];
      acc[i][j] = fmaxf(v, 0.f) + aa * fminf(v, 0.f);
    }

  if (MODE == 1) {
    float cmax[8];
#pragma unroll
    for (int j = 0; j < 8; ++j) {
      cmax[j] = acc[0][j];
#pragma unroll
      for (int i = 1; i < 8; ++i) cmax[j] = fmaxf(cmax[j], acc[i][j]);
    }
    __syncthreads();
#pragma unroll
    for (int j = 0; j < 8; ++j) At[(t & 15) * 132 + c0 + j] = cmax[j];
    __syncthreads();
    if (t < 128) {
      float m = At[t];
      for (int rr = 1; rr < 16; ++rr) m = fmaxf(m, At[rr * 132 + t]);
      atomicMax(&gmax[cbb + t], fenc(m));
    }
  } else {
#pragma unroll
    for (int i = 0; i < 8; ++i) {
      f4 s0 = {acc[i][0], acc[i][1], acc[i][2], acc[i][3]};
      f4 s1 = {acc[i][4], acc[i][5], acc[i][6], acc[i][7]};
      float* cp = &Cm[(size_t)(rb + r0 + i) * ldc + cbb + c0];
      *(f4*)cp = s0;
      *(f4*)(cp + 4) = s1;
    }
  }
}

// ---------------- bias5[c] = sum_j g[j] * W5[192+j][c] ----------------
__global__ void bias5_kernel(const unsigned* __restrict__ gmax, const float* __restrict__ W5,
                             float* __restrict__ bias5) {
  __shared__ float gs[1024];
  __shared__ float pm[4 * 256];
  int t = threadIdx.x;  // 1024 threads
  gs[t] = fdec(gmax[t]);
  __syncthreads();
  int c = t & 255, p = t >> 8;
  float acc = 0.f;
  for (int j = p * 256; j < p * 256 + 256; ++j)
    acc = fmaf(gs[j], W5[(size_t)(192 + j) * 256 + c], acc);
  pm[p * 256 + c] = acc;
  __syncthreads();
  if (t < 256) bias5[t] = pm[t] + pm[256 + t] + pm[512 + t] + pm[768 + t];
}

// ---------------- final [N,128]@[128,3] + prelu + hidden passthrough ----------------
// COUT = 3 (NOT 20 -- K is 20, COUT is 3). out has N*3+1 floats.
__global__ __launch_bounds__(256, 2)
void w8_kernel(const float* __restrict__ A, const float* __restrict__ W8,
               const float* __restrict__ pptr, const float* __restrict__ hidden,
               float* __restrict__ out) {
  __shared__ __align__(16) float As[64 * 132];   // padded: (4r+j)%32 -> 2-way, free
  __shared__ float W8s[128 * COUT];
  int t = threadIdx.x;
  int rb = blockIdx.x * 64;
  for (int idx = t; idx < 128 * COUT; idx += 256) W8s[idx] = W8[idx];
  for (int idx = t; idx < 64 * 32; idx += 256) {
    int r = idx >> 5, c4 = idx & 31;
    *(f4*)&As[r * 132 + c4 * 4] = *(const f4*)&A[(size_t)(rb + r) * 128 + c4 * 4];
  }
  const float a = *pptr;
  __syncthreads();
  int r = t >> 2, c = t & 3;   // 4 threads per row; lane c==3 idles
  if (c < COUT) {
    float acc = 0.f;
#pragma unroll 8
    for (int j = 0; j < 128; ++j)
      acc = fmaf(As[r * 132 + j], W8s[j * COUT + c], acc);
    float v = fmaxf(acc, 0.f) + a * fminf(acc, 0.f);
    out[(size_t)(rb + r) * COUT + c] = v;
  }
  if (blockIdx.x == 0 && t == 0) out[(size_t)NPTS * COUT] = hidden[0];
}

// ---------------- host launch ----------------
extern "C" void kernel_launch(void* const* d_in, const int* in_sizes, int n_in,
                              void* d_out, int out_size, void* d_ws, size_t ws_size,
                              hipStream_t stream) {
  (void)in_sizes; (void)n_in; (void)out_size; (void)ws_size;
  const float* x      = (const float*)d_in[0];
  const float* hidden = (const float*)d_in[1];
  const float* W1a = (const float*)d_in[2];
  const float* p1a = (const float*)d_in[3];
  const float* W1b = (const float*)d_in[4];
  const float* p1b = (const float*)d_in[5];
  const float* W2a = (const float*)d_in[6];
  const float* p2a = (const float*)d_in[7];
  const float* W2b = (const float*)d_in[8];
  const float* p2b = (const float*)d_in[9];
  const float* W3  = (const float*)d_in[10];
  const float* p3  = (const float*)d_in[11];
  const float* W4  = (const float*)d_in[12];
  const float* p4  = (const float*)d_in[13];
  const float* W5  = (const float*)d_in[14];
  const float* p5  = (const float*)d_in[15];
  const float* W6  = (const float*)d_in[16];
  const float* p6  = (const float*)d_in[17];
  const float* W7  = (const float*)d_in[18];
  const float* p7  = (const float*)d_in[19];
  const float* W8  = (const float*)d_in[20];
  const float* p8  = (const float*)d_in[21];
  float* out = (float*)d_out;

  char* ws = (char*)d_ws;
  size_t off = 0;
  auto carve = [&](size_t bytes) -> void* {
    void* p = ws + off;
    off = (off + bytes + 255) & ~(size_t)255;
    return p;
  };
  float*    x4    = (float*)   carve((size_t)NPTS * 192 * 4);  // [x1|x2|x3], ld=192 (reused as h7)
  float*    vn    = (float*)   carve((size_t)NPTS * 4);
  int*      ind   = (int*)     carve((size_t)NPTS * KK * 4);
  unsigned* gmax  = (unsigned*)carve(1024 * 4);
  float*    bias5 = (float*)   carve(256 * 4);
  float*    h5    = (float*)   carve((size_t)NPTS * 256 * 4);  // also pd region (knn phase)
  float*    h6    = (float*)   carve((size_t)NPTS * 256 * 4);  // also pi region (knn phase)
  float* pd = h5;
  int*   pi = (int*)h6;
  float* h7 = x4;  // x4 dead after W5 GEMM

  // ---- stage 1: knn(x, C=3) + edgeconv1 -> x4[:, 0:64] ----
  norms_kernel<3><<<64, 256, 0, stream>>>(x, 3, vn);
  knn_kernel<3><<<dim3(128, 4), 256, 0, stream>>>(x, 3, vn, pd, pi);
  knn_merge_kernel<<<64, 256, 0, stream>>>(pd, pi, ind);
  edgeconv_kernel<3, true><<<512, 256, 0, stream>>>(x, 3, ind, W1a, p1a, W1b, p1b, x4 + 0, 192);

  // ---- stage 2: knn(x1) + edgeconv2 -> x4[:, 64:128] ----
  norms_kernel<64><<<64, 256, 0, stream>>>(x4 + 0, 192, vn);
  knn_kernel<64><<<dim3(128, 4), 256, 0, stream>>>(x4 + 0, 192, vn, pd, pi);
  knn_merge_kernel<<<64, 256, 0, stream>>>(pd, pi, ind);
  edgeconv_kernel<64, true><<<512, 256, 0, stream>>>(x4 + 0, 192, ind, W2a, p2a, W2b, p2b, x4 + 64, 192);

  // ---- stage 3: knn(x2) + edgeconv3 -> x4[:, 128:192] ----
  norms_kernel<64><<<64, 256, 0, stream>>>(x4 + 64, 192, vn);
  knn_kernel<64><<<dim3(128, 4), 256, 0, stream>>>(x4 + 64, 192, vn, pd, pi);
  knn_merge_kernel<<<64, 256, 0, stream>>>(pd, pi, ind);
  edgeconv_kernel<64, false><<<512, 256, 0, stream>>>(x4 + 64, 192, ind, W3, p3, nullptr, nullptr, x4 + 128, 192);

  // ---- x5 = prelu(x4@W4); g = colmax(x5) ----
  initg_kernel<<<4, 256, 0, stream>>>(gmax);
  gemm_kernel<1><<<dim3(128, 8), 256, 0, stream>>>(x4, 192, W4, 1024, nullptr, p4, nullptr, 0, 192, gmax);

  // ---- bias5 = g @ W5[192:1216] ----
  bias5_kernel<<<1, 1024, 0, stream>>>(gmax, W5, bias5);

  // ---- h5 = prelu(x4@W5[0:192] + bias5) ----
  gemm_kernel<2><<<dim3(128, 2), 256, 0, stream>>>(x4, 192, W5, 256, bias5, p5, h5, 256, 192, nullptr);
  // ---- h6 = prelu(h5@W6) ----
  gemm_kernel<0><<<dim3(128, 2), 256, 0, stream>>>(h5, 256, W6, 256, nullptr, p6, h6, 256, 256, nullptr);
  // ---- h7 = prelu(h6@W7) ----
  gemm_kernel<0><<<dim3(128, 1), 256, 0, stream>>>(h6, 256, W7, 128, nullptr, p7, h7, 128, 256, nullptr);
  // ---- out = prelu(h7@W8); out[N*3] = hidden ----
  w8_kernel<<<256, 256, 0, stream>>>(h7, W8, p8, hidden, out);
}

// Round 4
// 5265.825 us; speedup vs baseline: 4.0066x; 4.0066x over previous
//
#include <hip/hip_runtime.h>
#include <hip/hip_bf16.h>
#include <float.h>

#define NPTS 16384
#define KK 20
#define COUT 3
#define SURV_CAP 256

typedef float f4 __attribute__((ext_vector_type(4)));

// ---------------- sorted top-20 insert, values only ----------------
__device__ __forceinline__ void ins20(float (&td)[KK], float &kmax, float nd) {
  float cd = nd;
#pragma unroll
  for (int j = 0; j < KK; ++j) {
    float t0 = td[j];
    bool lt = cd < t0;
    td[j] = lt ? cd : t0;
    cd = lt ? t0 : cd;
  }
  kmax = td[KK - 1];
}

// ---------------- sorted top-20 insert, (value, index) ----------------
__device__ __forceinline__ void ins20p(float (&td)[KK], int (&ti)[KK],
                                       float &kmax, float nd, int ni) {
  float cd = nd; int ci = ni;
#pragma unroll
  for (int j = 0; j < KK; ++j) {
    float t0 = td[j]; int t1 = ti[j];
    bool lt = cd < t0;
    td[j] = lt ? cd : t0;  ti[j] = lt ? ci : t1;
    cd = lt ? t0 : cd;     ci = lt ? t1 : ci;
  }
  kmax = td[KK - 1];
}

// ---------------- row squared norms ----------------
template<int C>
__global__ void norms_kernel(const float* __restrict__ X, int ldx, float* __restrict__ vn) {
  int i = blockIdx.x * 256 + threadIdx.x;
  if (i >= NPTS) return;
  const float* row = X + (size_t)i * ldx;
  float s = 0.f;
#pragma unroll
  for (int c = 0; c < C; ++c) s = fmaf(row[c], row[c], s);
  vn[i] = s;
}

// ---------------- phase S: per-query threshold from stride-4 sample ------------
// grid 256 x 256. Block = 64 queries x 4 sample-splits. Also zeroes cnt[q].
// s-value = vn[c] - 2*dot(q,c): same ordering as squared distance per query.
template<int C>
__global__ __launch_bounds__(256, 2)
void sampleT_kernel(const float* __restrict__ X, int ldx, const float* __restrict__ vn,
                    float* __restrict__ T, unsigned* __restrict__ cnt) {
  __shared__ float Tp[4][64][KK];
  const int t = threadIdx.x;
  const int ql = t & 63, w = t >> 6;
  const int q = blockIdx.x * 64 + ql;

  float qreg[C];
#pragma unroll
  for (int d = 0; d < C; ++d) qreg[d] = X[(size_t)q * ldx + d];

  float td[KK];
#pragma unroll
  for (int j = 0; j < KK; ++j) td[j] = FLT_MAX;
  float kmax = FLT_MAX;

  for (int s = 0; s < 1024; ++s) {
    const int c = (w * 1024 + s) * 4;          // wave-uniform candidate
    const float* crow = X + (size_t)c * ldx;
    float d0 = 0.f, d1 = 0.f, d2 = 0.f, d3 = 0.f;
    if constexpr (C >= 4) {
#pragma unroll
      for (int d = 0; d + 3 < C; d += 4) {
        d0 = fmaf(crow[d], qreg[d], d0);
        d1 = fmaf(crow[d + 1], qreg[d + 1], d1);
        d2 = fmaf(crow[d + 2], qreg[d + 2], d2);
        d3 = fmaf(crow[d + 3], qreg[d + 3], d3);
      }
    }
    if constexpr ((C & 3) != 0) {
#pragma unroll
      for (int d = C & ~3; d < C; ++d) d0 = fmaf(crow[d], qreg[d], d0);
    }
    float dot = (d0 + d1) + (d2 + d3);
    float sv = fmaf(-2.f, dot, vn[c]);
    if (sv < kmax) ins20(td, kmax, sv);
  }
#pragma unroll
  for (int j = 0; j < KK; ++j) Tp[w][ql][j] = td[j];
  __syncthreads();
  if (t < 64) {
    float md[KK];
#pragma unroll
    for (int j = 0; j < KK; ++j) md[j] = FLT_MAX;
    float km = FLT_MAX;
    for (int ww = 0; ww < 4; ++ww)
#pragma unroll
      for (int j = 0; j < KK; ++j) {
        float v = Tp[ww][t][j];
        if (v < km) ins20(md, km, v);
      }
    int qq = blockIdx.x * 64 + t;
    // pad covers dot-reassociation ulps between sample (4-chain) and filter (1-chain)
    T[qq] = md[KK - 1] + 1e-4f * (fabsf(md[KK - 1]) + 1.0f);
    cnt[qq] = 0u;
  }
}

// ---------------- phase F: tiled distance GEMM + threshold filter -> survivors ----
// grid (128, 8) x 256. Per block: 128 queries x 2048 candidates (16 tiles).
template<int C>
__global__ __launch_bounds__(256, 4)
void knn_filter_kernel(const float* __restrict__ X, int ldx, const float* __restrict__ vn,
                       const float* __restrict__ T,
                       float* __restrict__ survd, int* __restrict__ survi,
                       unsigned* __restrict__ cnt) {
  constexpr int QT = 128, CT = 128, CSTR = CT + 4;
  constexpr int KC = (C < 32) ? C : 32;
  constexpr int NCH = (C + KC - 1) / KC;
  __shared__ __align__(16) float Qs[KC * QT];
  __shared__ __align__(16) float Cs[KC * CSTR];
  __shared__ float cnorm[CT];
  __shared__ float Tsl[QT];

  const int t = threadIdx.x;
  const int qb = blockIdx.x * QT;
  const int cbase = blockIdx.y * (NPTS / 8);

  if (t < QT) Tsl[t] = T[qb + t];

  const int tq = t & 15, tc = t >> 4;
  const int q0 = tq * 8, c0 = tc * 8;

  for (int ct = 0; ct < (NPTS / 8) / CT; ++ct) {
    const int cb = cbase + ct * CT;

    float acc[8][8];
#pragma unroll
    for (int i = 0; i < 8; ++i)
#pragma unroll
      for (int j = 0; j < 8; ++j) acc[i][j] = 0.f;

    for (int kc = 0; kc < NCH; ++kc) {
      __syncthreads();  // prior tile finalize / Tsl load done
      for (int idx = t; idx < KC * QT; idx += 256) {
        int q = idx / KC, c = idx - q * KC;
        Qs[c * QT + q] = X[(size_t)(qb + q) * ldx + kc * KC + c];
      }
      for (int idx = t; idx < KC * CT; idx += 256) {
        int j = idx / KC, c = idx - j * KC;
        Cs[c * CSTR + j] = X[(size_t)(cb + j) * ldx + kc * KC + c];
      }
      if (kc == 0 && t < CT) cnorm[t] = vn[cb + t];
      __syncthreads();

#pragma unroll 2
      for (int d = 0; d < KC; ++d) {
        f4 qa = *(const f4*)&Qs[d * QT + q0];
        f4 qbv = *(const f4*)&Qs[d * QT + q0 + 4];
        f4 ca = *(const f4*)&Cs[d * CSTR + c0];
        f4 cbv = *(const f4*)&Cs[d * CSTR + c0 + 4];
        float qr[8] = {qa[0], qa[1], qa[2], qa[3], qbv[0], qbv[1], qbv[2], qbv[3]};
        float cr[8] = {ca[0], ca[1], ca[2], ca[3], cbv[0], cbv[1], cbv[2], cbv[3]};
#pragma unroll
        for (int i = 0; i < 8; ++i)
#pragma unroll
          for (int j = 0; j < 8; ++j)
            acc[i][j] = fmaf(qr[i], cr[j], acc[i][j]);
      }
    }

    // s = vn_c - 2<q,c>; append survivors s <= T[q]
#pragma unroll
    for (int j = 0; j < 8; ++j) {
      float cv = cnorm[c0 + j];
#pragma unroll
      for (int i = 0; i < 8; ++i)
        acc[i][j] = fmaf(-2.f, acc[i][j], cv);
    }
#pragma unroll
    for (int i = 0; i < 8; ++i) {
      const float tcut = Tsl[q0 + i];
      const int q = qb + q0 + i;
#pragma unroll
      for (int j = 0; j < 8; ++j) {
        if (acc[i][j] <= tcut) {
          unsigned p = atomicAdd(&cnt[q], 1u);
          if (p < SURV_CAP) {
            survd[(size_t)q * SURV_CAP + p] = acc[i][j];
            survi[(size_t)q * SURV_CAP + p] = cb + c0 + j;
          }
        }
      }
    }
  }
}

// ---------------- phase Sel: exact top-20 among survivors ----------------
template<int C>
__global__ __launch_bounds__(256, 2)
void select_kernel(const float* __restrict__ X, int ldx, const float* __restrict__ vn,
                   const float* __restrict__ survd, const int* __restrict__ survi,
                   const unsigned* __restrict__ cnt, int* __restrict__ ind) {
  const int q = blockIdx.x * 256 + threadIdx.x;
  const unsigned n = cnt[q];
  float td[KK]; int ti[KK];
#pragma unroll
  for (int j = 0; j < KK; ++j) { td[j] = FLT_MAX; ti[j] = 0; }
  float kmax = FLT_MAX;
  if (n <= SURV_CAP) {
    for (unsigned i = 0; i < n; ++i) {
      float d = survd[(size_t)q * SURV_CAP + i];
      if (d < kmax) ins20p(td, ti, kmax, d, survi[(size_t)q * SURV_CAP + i]);
    }
  } else {
    // overflow fallback (P ~ 1e-10): exact serial full scan
    for (int c = 0; c < NPTS; ++c) {
      float dot = 0.f;
      for (int d = 0; d < C; ++d)
        dot = fmaf(X[(size_t)c * ldx + d], X[(size_t)q * ldx + d], dot);
      float sv = fmaf(-2.f, dot, vn[c]);
      if (sv < kmax) ins20p(td, ti, kmax, sv, c);
    }
  }
#pragma unroll
  for (int j = 0; j < KK; ++j) ind[q * KK + j] = ti[j];
}

// ---------------- edge conv: gather + (f@W1 prelu [@W2 prelu]) + max over k ----------
template<int CIN, bool TWO>
__global__ __launch_bounds__(256, 2)
void edgeconv_kernel(const float* __restrict__ X, int ldx,
                     const int* __restrict__ ind,
                     const float* __restrict__ W1, const float* __restrict__ p1p,
                     const float* __restrict__ W2, const float* __restrict__ p2p,
                     float* __restrict__ Y, int ldy) {
  constexpr int F = 2 * CIN;
  __shared__ __align__(16) float ft[4][F * KK];
  __shared__ __align__(16) float h1t[4][TWO ? 64 * KK : 4];
  __shared__ float xis[4][CIN];
  __shared__ int nbs[4][KK];

  const int t = threadIdx.x;
  const int w = t >> 6, l = t & 63;
  const float a1 = *p1p;
  float a2 = 0.f;
  if constexpr (TWO) a2 = *p2p;

  for (int pp = 0; pp < 8; ++pp) {
    const int i = blockIdx.x * 32 + w * 8 + pp;
    __syncthreads();
    if (l < CIN) xis[w][l] = X[(size_t)i * ldx + l];
    if (l < KK) nbs[w][l] = ind[i * KK + l];
    __syncthreads();
    for (int idx = l; idx < F * KK; idx += 64) {
      int j = idx / KK, k = idx - j * KK;
      float v;
      if (j < CIN) v = X[(size_t)nbs[w][k] * ldx + j] - xis[w][j];
      else v = xis[w][j - CIN];
      ft[w][idx] = v;
    }
    __syncthreads();

    if constexpr (TWO) {
#pragma unroll
      for (int kb = 0; kb < KK; kb += 4) {
        float s0 = 0.f, s1 = 0.f, s2 = 0.f, s3 = 0.f;
#pragma unroll 4
        for (int j = 0; j < F; ++j) {
          f4 fv = *(const f4*)&ft[w][j * KK + kb];
          float wv = W1[j * 64 + l];
          s0 = fmaf(fv[0], wv, s0);
          s1 = fmaf(fv[1], wv, s1);
          s2 = fmaf(fv[2], wv, s2);
          s3 = fmaf(fv[3], wv, s3);
        }
        f4 h;
        h[0] = fmaxf(s0, 0.f) + a1 * fminf(s0, 0.f);
        h[1] = fmaxf(s1, 0.f) + a1 * fminf(s1, 0.f);
        h[2] = fmaxf(s2, 0.f) + a1 * fminf(s2, 0.f);
        h[3] = fmaxf(s3, 0.f) + a1 * fminf(s3, 0.f);
        *(f4*)&h1t[w][l * KK + kb] = h;
      }
      __syncthreads();
      float mx = -FLT_MAX;
#pragma unroll
      for (int kb = 0; kb < KK; kb += 4) {
        float s0 = 0.f, s1 = 0.f, s2 = 0.f, s3 = 0.f;
#pragma unroll 4
        for (int j = 0; j < 64; ++j) {
          f4 hv = *(const f4*)&h1t[w][j * KK + kb];
          float wv = W2[j * 64 + l];
          s0 = fmaf(hv[0], wv, s0);
          s1 = fmaf(hv[1], wv, s1);
          s2 = fmaf(hv[2], wv, s2);
          s3 = fmaf(hv[3], wv, s3);
        }
        float v0 = fmaxf(s0, 0.f) + a2 * fminf(s0, 0.f);
        float v1 = fmaxf(s1, 0.f) + a2 * fminf(s1, 0.f);
        float v2 = fmaxf(s2, 0.f) + a2 * fminf(s2, 0.f);
        float v3 = fmaxf(s3, 0.f) + a2 * fminf(s3, 0.f);
        mx = fmaxf(mx, fmaxf(fmaxf(v0, v1), fmaxf(v2, v3)));
      }
      Y[(size_t)i * ldy + l] = mx;
    } else {
      float mx = -FLT_MAX;
#pragma unroll
      for (int kb = 0; kb < KK; kb += 4) {
        float s0 = 0.f, s1 = 0.f, s2 = 0.f, s3 = 0.f;
#pragma unroll 4
        for (int j = 0; j < F; ++j) {
          f4 fv = *(const f4*)&ft[w][j * KK + kb];
          float wv = W1[j * 64 + l];
          s0 = fmaf(fv[0], wv, s0);
          s1 = fmaf(fv[1], wv, s1);
          s2 = fmaf(fv[2], wv, s2);
          s3 = fmaf(fv[3], wv, s3);
        }
        float v0 = fmaxf(s0, 0.f) + a1 * fminf(s0, 0.f);
        float v1 = fmaxf(s1, 0.f) + a1 * fminf(s1, 0.f);
        float v2 = fmaxf(s2, 0.f) + a1 * fminf(s2, 0.f);
        float v3 = fmaxf(s3, 0.f) + a1 * fminf(s3, 0.f);
        mx = fmaxf(mx, fmaxf(fmaxf(v0, v1), fmaxf(v2, v3)));
      }
      Y[(size_t)i * ldy + l] = mx;
    }
  }
}

// ---------------- ordered-float encode for atomicMax ----------------
__device__ __forceinline__ unsigned fenc(float f) {
  unsigned u = __float_as_uint(f);
  return (u & 0x80000000u) ? ~u : (u | 0x80000000u);
}
__device__ __forceinline__ float fdec(unsigned u) {
  return (u & 0x80000000u) ? __uint_as_float(u & 0x7fffffffu) : __uint_as_float(~u);
}

__global__ void initg_kernel(unsigned* __restrict__ g) {
  g[blockIdx.x * 256 + threadIdx.x] = 0x007FFFFFu;  // fenc(-inf)
}

// ---------------- generic fp32 GEMM + prelu; MODE: 0 store, 1 colmax, 2 bias+store ----
template<int MODE>
__global__ __launch_bounds__(256, 2)
void gemm_kernel(const float* __restrict__ A, int lda,
                 const float* __restrict__ W, int ldw,
                 const float* __restrict__ bias,
                 const float* __restrict__ pptr,
                 float* __restrict__ Cm, int ldc, int Ktot,
                 unsigned* __restrict__ gmax) {
  __shared__ __align__(16) float At[16 * 132];
  __shared__ __align__(16) float Ws[16 * 128];
  const int t = threadIdx.x;
  const int rb = blockIdx.x * 128, cbb = blockIdx.y * 128;
  const int r0 = (t & 15) * 8, c0 = (t >> 4) * 8;
  const float aa = *pptr;

  float acc[8][8];
#pragma unroll
  for (int i = 0; i < 8; ++i)
#pragma unroll
    for (int j = 0; j < 8; ++j) acc[i][j] = 0.f;

  const int sr = t >> 1, skh = (t & 1) * 8;
  const int wk = t >> 4, wc = (t & 15) * 8;

  for (int k0 = 0; k0 < Ktot; k0 += 16) {
    __syncthreads();
    {
      const float* ap = &A[(size_t)(rb + sr) * lda + k0 + skh];
      f4 v0 = *(const f4*)ap;
      f4 v1 = *(const f4*)(ap + 4);
#pragma unroll
      for (int e = 0; e < 4; ++e) {
        At[(skh + e) * 132 + sr] = v0[e];
        At[(skh + 4 + e) * 132 + sr] = v1[e];
      }
      const float* wp = &W[(size_t)(k0 + wk) * ldw + cbb + wc];
      *(f4*)&Ws[wk * 128 + wc] = *(const f4*)wp;
      *(f4*)&Ws[wk * 128 + wc + 4] = *(const f4*)(wp + 4);
    }
    __syncthreads();
#pragma unroll 4
    for (int d = 0; d < 16; ++d) {
      f4 qa = *(const f4*)&At[d * 132 + r0];
      f4 qb = *(const f4*)&At[d * 132 + r0 + 4];
      f4 wa = *(const f4*)&Ws[d * 128 + c0];
      f4 wb = *(const f4*)&Ws[d * 128 + c0 + 4];
      float qr[8] = {qa[0], qa[1], qa[2], qa[3], qb[0], qb[1], qb[2], qb[3]};
      float wr[8] = {wa[0], wa[1], wa[2], wa[3], wb[0], wb[1], wb[2], wb[3]};
#pragma unroll
      for (int i = 0; i < 8; ++i)
#pragma unroll
        for (int j = 0; j < 8; ++j)
          acc[i][j] = fmaf(qr[i], wr[j], acc[i][j]);
    }
  }

  float bv[8];
#pragma unroll
  for (int j = 0; j < 8; ++j) bv[j] = (MODE == 2) ? bias[cbb + c0 + j] : 0.f;
#pragma unroll
  for (int i = 0; i < 8; ++i)
#pragma unroll
    for (int j = 0; j < 8; ++j) {
      float v = acc[i][j] + bv[j];
      acc[i][j] = fmaxf(v, 0.f) + aa * fminf(v, 0.f);
    }

  if (MODE == 1) {
    float cmax[8];
#pragma unroll
    for (int j = 0; j < 8; ++j) {
      cmax[j] = acc[0][j];
#pragma unroll
      for (int i = 1; i < 8; ++i) cmax[j] = fmaxf(cmax[j], acc[i][j]);
    }
    __syncthreads();
#pragma unroll
    for (int j = 0; j < 8; ++j) At[(t & 15) * 132 + c0 + j] = cmax[j];
    __syncthreads();
    if (t < 128) {
      float m = At[t];
      for (int rr = 1; rr < 16; ++rr) m = fmaxf(m, At[rr * 132 + t]);
      atomicMax(&gmax[cbb + t], fenc(m));
    }
  } else {
#pragma unroll
    for (int i = 0; i < 8; ++i) {
      f4 s0 = {acc[i][0], acc[i][1], acc[i][2], acc[i][3]};
      f4 s1 = {acc[i][4], acc[i][5], acc[i][6], acc[i][7]};
      float* cp = &Cm[(size_t)(rb + r0 + i) * ldc + cbb + c0];
      *(f4*)cp = s0;
      *(f4*)(cp + 4) = s1;
    }
  }
}

// ---------------- bias5[c] = sum_j g[j] * W5[192+j][c] ----------------
__global__ void bias5_kernel(const unsigned* __restrict__ gmax, const float* __restrict__ W5,
                             float* __restrict__ bias5) {
  __shared__ float gs[1024];
  __shared__ float pm[4 * 256];
  int t = threadIdx.x;  // 1024 threads
  gs[t] = fdec(gmax[t]);
  __syncthreads();
  int c = t & 255, p = t >> 8;
  float acc = 0.f;
  for (int j = p * 256; j < p * 256 + 256; ++j)
    acc = fmaf(gs[j], W5[(size_t)(192 + j) * 256 + c], acc);
  pm[p * 256 + c] = acc;
  __syncthreads();
  if (t < 256) bias5[t] = pm[t] + pm[256 + t] + pm[512 + t] + pm[768 + t];
}

// ---------------- final [N,128]@[128,3] + prelu + hidden passthrough ----------------
__global__ __launch_bounds__(256, 2)
void w8_kernel(const float* __restrict__ A, const float* __restrict__ W8,
               const float* __restrict__ pptr, const float* __restrict__ hidden,
               float* __restrict__ out) {
  __shared__ __align__(16) float As[64 * 132];
  __shared__ float W8s[128 * COUT];
  int t = threadIdx.x;
  int rb = blockIdx.x * 64;
  for (int idx = t; idx < 128 * COUT; idx += 256) W8s[idx] = W8[idx];
  for (int idx = t; idx < 64 * 32; idx += 256) {
    int r = idx >> 5, c4 = idx & 31;
    *(f4*)&As[r * 132 + c4 * 4] = *(const f4*)&A[(size_t)(rb + r) * 128 + c4 * 4];
  }
  const float a = *pptr;
  __syncthreads();
  int r = t >> 2, c = t & 3;
  if (c < COUT) {
    float acc = 0.f;
#pragma unroll 8
    for (int j = 0; j < 128; ++j)
      acc = fmaf(As[r * 132 + j], W8s[j * COUT + c], acc);
    float v = fmaxf(acc, 0.f) + a * fminf(acc, 0.f);
    out[(size_t)(rb + r) * COUT + c] = v;
  }
  if (blockIdx.x == 0 && t == 0) out[(size_t)NPTS * COUT] = hidden[0];
}

// ---------------- host launch ----------------
extern "C" void kernel_launch(void* const* d_in, const int* in_sizes, int n_in,
                              void* d_out, int out_size, void* d_ws, size_t ws_size,
                              hipStream_t stream) {
  (void)in_sizes; (void)n_in; (void)out_size; (void)ws_size;
  const float* x      = (const float*)d_in[0];
  const float* hidden = (const float*)d_in[1];
  const float* W1a = (const float*)d_in[2];
  const float* p1a = (const float*)d_in[3];
  const float* W1b = (const float*)d_in[4];
  const float* p1b = (const float*)d_in[5];
  const float* W2a = (const float*)d_in[6];
  const float* p2a = (const float*)d_in[7];
  const float* W2b = (const float*)d_in[8];
  const float* p2b = (const float*)d_in[9];
  const float* W3  = (const float*)d_in[10];
  const float* p3  = (const float*)d_in[11];
  const float* W4  = (const float*)d_in[12];
  const float* p4  = (const float*)d_in[13];
  const float* W5  = (const float*)d_in[14];
  const float* p5  = (const float*)d_in[15];
  const float* W6  = (const float*)d_in[16];
  const float* p6  = (const float*)d_in[17];
  const float* W7  = (const float*)d_in[18];
  const float* p7  = (const float*)d_in[19];
  const float* W8  = (const float*)d_in[20];
  const float* p8  = (const float*)d_in[21];
  float* out = (float*)d_out;

  char* ws = (char*)d_ws;
  size_t off = 0;
  auto carve = [&](size_t bytes) -> void* {
    void* p = ws + off;
    off = (off + bytes + 255) & ~(size_t)255;
    return p;
  };
  float*    x4    = (float*)   carve((size_t)NPTS * 192 * 4);  // [x1|x2|x3], ld=192 (reused as h7)
  float*    vn    = (float*)   carve((size_t)NPTS * 4);
  int*      ind   = (int*)     carve((size_t)NPTS * KK * 4);
  float*    T     = (float*)   carve((size_t)NPTS * 4);
  unsigned* cnt   = (unsigned*)carve((size_t)NPTS * 4);
  unsigned* gmax  = (unsigned*)carve(1024 * 4);
  float*    bias5 = (float*)   carve(256 * 4);
  float*    h5    = (float*)   carve((size_t)NPTS * 256 * 4);  // aliased: survd (knn phase)
  float*    h6    = (float*)   carve((size_t)NPTS * 256 * 4);  // aliased: survi (knn phase)
  float* survd = h5;
  int*   survi = (int*)h6;
  float* h7 = x4;  // x4 dead after W5 GEMM

  // ---- stage 1: knn(x, C=3) + edgeconv1 -> x4[:, 0:64] ----
  norms_kernel<3><<<64, 256, 0, stream>>>(x, 3, vn);
  sampleT_kernel<3><<<256, 256, 0, stream>>>(x, 3, vn, T, cnt);
  knn_filter_kernel<3><<<dim3(128, 8), 256, 0, stream>>>(x, 3, vn, T, survd, survi, cnt);
  select_kernel<3><<<64, 256, 0, stream>>>(x, 3, vn, survd, survi, cnt, ind);
  edgeconv_kernel<3, true><<<512, 256, 0, stream>>>(x, 3, ind, W1a, p1a, W1b, p1b, x4 + 0, 192);

  // ---- stage 2: knn(x1) + edgeconv2 -> x4[:, 64:128] ----
  norms_kernel<64><<<64, 256, 0, stream>>>(x4 + 0, 192, vn);
  sampleT_kernel<64><<<256, 256, 0, stream>>>(x4 + 0, 192, vn, T, cnt);
  knn_filter_kernel<64><<<dim3(128, 8), 256, 0, stream>>>(x4 + 0, 192, vn, T, survd, survi, cnt);
  select_kernel<64><<<64, 256, 0, stream>>>(x4 + 0, 192, vn, survd, survi, cnt, ind);
  edgeconv_kernel<64, true><<<512, 256, 0, stream>>>(x4 + 0, 192, ind, W2a, p2a, W2b, p2b, x4 + 64, 192);

  // ---- stage 3: knn(x2) + edgeconv3 -> x4[:, 128:192] ----
  norms_kernel<64><<<64, 256, 0, stream>>>(x4 + 64, 192, vn);
  sampleT_kernel<64><<<256, 256, 0, stream>>>(x4 + 64, 192, vn, T, cnt);
  knn_filter_kernel<64><<<dim3(128, 8), 256, 0, stream>>>(x4 + 64, 192, vn, T, survd, survi, cnt);
  select_kernel<64><<<64, 256, 0, stream>>>(x4 + 64, 192, vn, survd, survi, cnt, ind);
  edgeconv_kernel<64, false><<<512, 256, 0, stream>>>(x4 + 64, 192, ind, W3, p3, nullptr, nullptr, x4 + 128, 192);

  // ---- x5 = prelu(x4@W4); g = colmax(x5) ----
  initg_kernel<<<4, 256, 0, stream>>>(gmax);
  gemm_kernel<1><<<dim3(128, 8), 256, 0, stream>>>(x4, 192, W4, 1024, nullptr, p4, nullptr, 0, 192, gmax);

  // ---- bias5 = g @ W5[192:1216] ----
  bias5_kernel<<<1, 1024, 0, stream>>>(gmax, W5, bias5);

  // ---- h5 = prelu(x4@W5[0:192] + bias5) ----
  gemm_kernel<2><<<dim3(128, 2), 256, 0, stream>>>(x4, 192, W5, 256, bias5, p5, h5, 256, 192, nullptr);
  // ---- h6 = prelu(h5@W6) ----
  gemm_kernel<0><<<dim3(128, 2), 256, 0, stream>>>(h5, 256, W6, 256, nullptr, p6, h6, 256, 256, nullptr);
  // ---- h7 = prelu(h6@W7) ----
  gemm_kernel<0><<<dim3(128, 1), 256, 0, stream>>>(h6, 256, W7, 128, nullptr, p7, h7, 128, 256, nullptr);
  // ---- out = prelu(h7@W8); out[N*3] = hidden ----
  w8_kernel<<<256, 256, 0, stream>>>(h7, W8, p8, hidden, out);
}

// Round 5
// 4988.694 us; speedup vs baseline: 4.2292x; 1.0556x over previous
//
#include <hip/hip_runtime.h>
#include <hip/hip_bf16.h>
#include <float.h>

#define NPTS 16384
#define KK 20
#define COUT 3
#define SURV_CAP 256

typedef float f4 __attribute__((ext_vector_type(4)));

// ---------------- sorted top-20 insert, values only ----------------
__device__ __forceinline__ void ins20(float (&td)[KK], float &kmax, float nd) {
  float cd = nd;
#pragma unroll
  for (int j = 0; j < KK; ++j) {
    float t0 = td[j];
    bool lt = cd < t0;
    td[j] = lt ? cd : t0;
    cd = lt ? t0 : cd;
  }
  kmax = td[KK - 1];
}

// ---------------- sorted top-20 insert, (value, index) ----------------
__device__ __forceinline__ void ins20p(float (&td)[KK], int (&ti)[KK],
                                       float &kmax, float nd, int ni) {
  float cd = nd; int ci = ni;
#pragma unroll
  for (int j = 0; j < KK; ++j) {
    float t0 = td[j]; int t1 = ti[j];
    bool lt = cd < t0;
    td[j] = lt ? cd : t0;  ti[j] = lt ? ci : t1;
    cd = lt ? t0 : cd;     ci = lt ? t1 : ci;
  }
  kmax = td[KK - 1];
}

// ---------------- row squared norms ----------------
template<int C>
__global__ void norms_kernel(const float* __restrict__ X, int ldx, float* __restrict__ vn) {
  int i = blockIdx.x * 256 + threadIdx.x;
  if (i >= NPTS) return;
  const float* row = X + (size_t)i * ldx;
  float s = 0.f;
#pragma unroll
  for (int c = 0; c < C; ++c) s = fmaf(row[c], row[c], s);
  vn[i] = s;
}

// ---------------- phase S (v2): per-query threshold from stride-4 sample ----------
// Block = 8 query-groups x 32 lanes. Each lane scans a 128-candidate substream of
// the shared LDS-staged sample (m=4096), keeping a per-lane top-20; one lane per
// group merges 32 sorted lists. Grid 2048. Also zeroes cnt[q].
template<int C>
__global__ __launch_bounds__(256, 2)
void sampleT_kernel(const float* __restrict__ X, int ldx, const float* __restrict__ vn,
                    float* __restrict__ T, unsigned* __restrict__ cnt) {
  constexpr int GQ = 8, GL = 32;
  constexpr int CHUNK = 128;                 // candidates staged per chunk
  constexpr int CPL = CHUNK / GL;            // 4 candidates per lane per chunk
  constexpr int NCHK = 4096 / CHUNK;         // 32 chunks (m = 4096, stride 4)
  constexpr int CSTR = (C & 3) ? C : (C + 2);  // 64->66 (2-way banks), 3->3
  __shared__ __align__(16) float Cs[CHUNK * CSTR];
  __shared__ float cn[CHUNK];
  __shared__ float qsh[GQ][C];
  __shared__ float mrg[GQ][GL * KK];         // 20 KB

  const int t = threadIdx.x;
  const int g = t >> 5, l = t & 31;
  const int q = blockIdx.x * GQ + g;

  for (int idx = t; idx < GQ * C; idx += 256) {
    int gg = idx / C, d = idx - gg * C;
    qsh[gg][d] = X[(size_t)(blockIdx.x * GQ + gg) * ldx + d];
  }

  float td[KK];
#pragma unroll
  for (int j = 0; j < KK; ++j) td[j] = FLT_MAX;
  float kmax = FLT_MAX;

  for (int ck = 0; ck < NCHK; ++ck) {
    __syncthreads();   // prior chunk consumed (and qsh ready on first iter)
    for (int idx = t; idx < CHUNK * C; idx += 256) {
      int r = idx / C, d = idx - r * C;
      Cs[r * CSTR + d] = X[(size_t)((ck * CHUNK + r) * 4) * ldx + d];
    }
    if (t < CHUNK) cn[t] = vn[(ck * CHUNK + t) * 4];
    __syncthreads();
#pragma unroll
    for (int u = 0; u < CPL; ++u) {
      const int r = u * GL + l;
      const float* crow = &Cs[r * CSTR];
      float d0 = 0.f, d1 = 0.f, d2 = 0.f, d3 = 0.f;
      if constexpr (C >= 4) {
#pragma unroll
        for (int d = 0; d + 3 < C; d += 4) {
          d0 = fmaf(crow[d + 0], qsh[g][d + 0], d0);
          d1 = fmaf(crow[d + 1], qsh[g][d + 1], d1);
          d2 = fmaf(crow[d + 2], qsh[g][d + 2], d2);
          d3 = fmaf(crow[d + 3], qsh[g][d + 3], d3);
        }
      }
      if constexpr ((C & 3) != 0) {
#pragma unroll
        for (int d = C & ~3; d < C; ++d) d0 = fmaf(crow[d], qsh[g][d], d0);
      }
      float sv = fmaf(-2.f, (d0 + d1) + (d2 + d3), cn[r]);
      if (sv < kmax) ins20(td, kmax, sv);
    }
  }

#pragma unroll
  for (int j = 0; j < KK; ++j) mrg[g][l * KK + j] = td[j];
  __syncthreads();
  if (l == 0) {
    float md[KK];
#pragma unroll
    for (int j = 0; j < KK; ++j) md[j] = FLT_MAX;
    float km = FLT_MAX;
    for (int ll = 0; ll < GL; ++ll) {
      for (int j = 0; j < KK; ++j) {
        float v = mrg[g][ll * KK + j];
        if (v < km) ins20(md, km, v);
        else break;  // per-lane lists sorted ascending
      }
    }
    // pad covers dot-reassociation ulps between sample (4-chain) and filter (1-chain)
    T[q] = md[KK - 1] + 1e-4f * (fabsf(md[KK - 1]) + 1.0f);
    cnt[q] = 0u;
  }
}

// ---------------- phase F: tiled distance GEMM + threshold filter -> survivors ----
// grid (128, 8) x 256. Per block: 128 queries x 2048 candidates (16 tiles).
template<int C>
__global__ __launch_bounds__(256, 4)
void knn_filter_kernel(const float* __restrict__ X, int ldx, const float* __restrict__ vn,
                       const float* __restrict__ T,
                       float* __restrict__ survd, int* __restrict__ survi,
                       unsigned* __restrict__ cnt) {
  constexpr int QT = 128, CT = 128, CSTR = CT + 4;
  constexpr int KC = (C < 32) ? C : 32;
  constexpr int NCH = (C + KC - 1) / KC;
  __shared__ __align__(16) float Qs[KC * QT];
  __shared__ __align__(16) float Cs[KC * CSTR];
  __shared__ float cnorm[CT];
  __shared__ float Tsl[QT];

  const int t = threadIdx.x;
  const int qb = blockIdx.x * QT;
  const int cbase = blockIdx.y * (NPTS / 8);

  if (t < QT) Tsl[t] = T[qb + t];

  const int tq = t & 15, tc = t >> 4;
  const int q0 = tq * 8, c0 = tc * 8;

  for (int ct = 0; ct < (NPTS / 8) / CT; ++ct) {
    const int cb = cbase + ct * CT;

    float acc[8][8];
#pragma unroll
    for (int i = 0; i < 8; ++i)
#pragma unroll
      for (int j = 0; j < 8; ++j) acc[i][j] = 0.f;

    for (int kc = 0; kc < NCH; ++kc) {
      __syncthreads();  // prior tile finalize / Tsl load done
      for (int idx = t; idx < KC * QT; idx += 256) {
        int q = idx / KC, c = idx - q * KC;
        Qs[c * QT + q] = X[(size_t)(qb + q) * ldx + kc * KC + c];
      }
      for (int idx = t; idx < KC * CT; idx += 256) {
        int j = idx / KC, c = idx - j * KC;
        Cs[c * CSTR + j] = X[(size_t)(cb + j) * ldx + kc * KC + c];
      }
      if (kc == 0 && t < CT) cnorm[t] = vn[cb + t];
      __syncthreads();

#pragma unroll 2
      for (int d = 0; d < KC; ++d) {
        f4 qa = *(const f4*)&Qs[d * QT + q0];
        f4 qbv = *(const f4*)&Qs[d * QT + q0 + 4];
        f4 ca = *(const f4*)&Cs[d * CSTR + c0];
        f4 cbv = *(const f4*)&Cs[d * CSTR + c0 + 4];
        float qr[8] = {qa[0], qa[1], qa[2], qa[3], qbv[0], qbv[1], qbv[2], qbv[3]};
        float cr[8] = {ca[0], ca[1], ca[2], ca[3], cbv[0], cbv[1], cbv[2], cbv[3]};
#pragma unroll
        for (int i = 0; i < 8; ++i)
#pragma unroll
          for (int j = 0; j < 8; ++j)
            acc[i][j] = fmaf(qr[i], cr[j], acc[i][j]);
      }
    }

    // s = vn_c - 2<q,c>; append survivors s <= T[q]
#pragma unroll
    for (int j = 0; j < 8; ++j) {
      float cv = cnorm[c0 + j];
#pragma unroll
      for (int i = 0; i < 8; ++i)
        acc[i][j] = fmaf(-2.f, acc[i][j], cv);
    }
#pragma unroll
    for (int i = 0; i < 8; ++i) {
      const float tcut = Tsl[q0 + i];
      const int q = qb + q0 + i;
#pragma unroll
      for (int j = 0; j < 8; ++j) {
        if (acc[i][j] <= tcut) {
          unsigned p = atomicAdd(&cnt[q], 1u);
          if (p < SURV_CAP) {
            survd[(size_t)q * SURV_CAP + p] = acc[i][j];
            survi[(size_t)q * SURV_CAP + p] = cb + c0 + j;
          }
        }
      }
    }
  }
}

// ---------------- phase Sel: exact top-20 among survivors ----------------
template<int C>
__global__ __launch_bounds__(256, 2)
void select_kernel(const float* __restrict__ X, int ldx, const float* __restrict__ vn,
                   const float* __restrict__ survd, const int* __restrict__ survi,
                   const unsigned* __restrict__ cnt, int* __restrict__ ind) {
  const int q = blockIdx.x * 256 + threadIdx.x;
  const unsigned n = cnt[q];
  float td[KK]; int ti[KK];
#pragma unroll
  for (int j = 0; j < KK; ++j) { td[j] = FLT_MAX; ti[j] = 0; }
  float kmax = FLT_MAX;
  if (n <= SURV_CAP) {
    for (unsigned i = 0; i < n; ++i) {
      float d = survd[(size_t)q * SURV_CAP + i];
      if (d < kmax) ins20p(td, ti, kmax, d, survi[(size_t)q * SURV_CAP + i]);
    }
  } else {
    // overflow fallback (P ~ 1e-10): exact serial full scan
    for (int c = 0; c < NPTS; ++c) {
      float dot = 0.f;
      for (int d = 0; d < C; ++d)
        dot = fmaf(X[(size_t)c * ldx + d], X[(size_t)q * ldx + d], dot);
      float sv = fmaf(-2.f, dot, vn[c]);
      if (sv < kmax) ins20p(td, ti, kmax, sv, c);
    }
  }
#pragma unroll
  for (int j = 0; j < KK; ++j) ind[q * KK + j] = ti[j];
}

// ---------------- edge conv: gather + (f@W1 prelu [@W2 prelu]) + max over k ----------
template<int CIN, bool TWO>
__global__ __launch_bounds__(256, 2)
void edgeconv_kernel(const float* __restrict__ X, int ldx,
                     const int* __restrict__ ind,
                     const float* __restrict__ W1, const float* __restrict__ p1p,
                     const float* __restrict__ W2, const float* __restrict__ p2p,
                     float* __restrict__ Y, int ldy) {
  constexpr int F = 2 * CIN;
  __shared__ __align__(16) float ft[4][F * KK];
  __shared__ __align__(16) float h1t[4][TWO ? 64 * KK : 4];
  __shared__ float xis[4][CIN];
  __shared__ int nbs[4][KK];

  const int t = threadIdx.x;
  const int w = t >> 6, l = t & 63;
  const float a1 = *p1p;
  float a2 = 0.f;
  if constexpr (TWO) a2 = *p2p;

  for (int pp = 0; pp < 8; ++pp) {
    const int i = blockIdx.x * 32 + w * 8 + pp;
    __syncthreads();
    if (l < CIN) xis[w][l] = X[(size_t)i * ldx + l];
    if (l < KK) nbs[w][l] = ind[i * KK + l];
    __syncthreads();
    for (int idx = l; idx < F * KK; idx += 64) {
      int j = idx / KK, k = idx - j * KK;
      float v;
      if (j < CIN) v = X[(size_t)nbs[w][k] * ldx + j] - xis[w][j];
      else v = xis[w][j - CIN];
      ft[w][idx] = v;
    }
    __syncthreads();

    if constexpr (TWO) {
#pragma unroll
      for (int kb = 0; kb < KK; kb += 4) {
        float s0 = 0.f, s1 = 0.f, s2 = 0.f, s3 = 0.f;
#pragma unroll 4
        for (int j = 0; j < F; ++j) {
          f4 fv = *(const f4*)&ft[w][j * KK + kb];
          float wv = W1[j * 64 + l];
          s0 = fmaf(fv[0], wv, s0);
          s1 = fmaf(fv[1], wv, s1);
          s2 = fmaf(fv[2], wv, s2);
          s3 = fmaf(fv[3], wv, s3);
        }
        f4 h;
        h[0] = fmaxf(s0, 0.f) + a1 * fminf(s0, 0.f);
        h[1] = fmaxf(s1, 0.f) + a1 * fminf(s1, 0.f);
        h[2] = fmaxf(s2, 0.f) + a1 * fminf(s2, 0.f);
        h[3] = fmaxf(s3, 0.f) + a1 * fminf(s3, 0.f);
        *(f4*)&h1t[w][l * KK + kb] = h;
      }
      __syncthreads();
      float mx = -FLT_MAX;
#pragma unroll
      for (int kb = 0; kb < KK; kb += 4) {
        float s0 = 0.f, s1 = 0.f, s2 = 0.f, s3 = 0.f;
#pragma unroll 4
        for (int j = 0; j < 64; ++j) {
          f4 hv = *(const f4*)&h1t[w][j * KK + kb];
          float wv = W2[j * 64 + l];
          s0 = fmaf(hv[0], wv, s0);
          s1 = fmaf(hv[1], wv, s1);
          s2 = fmaf(hv[2], wv, s2);
          s3 = fmaf(hv[3], wv, s3);
        }
        float v0 = fmaxf(s0, 0.f) + a2 * fminf(s0, 0.f);
        float v1 = fmaxf(s1, 0.f) + a2 * fminf(s1, 0.f);
        float v2 = fmaxf(s2, 0.f) + a2 * fminf(s2, 0.f);
        float v3 = fmaxf(s3, 0.f) + a2 * fminf(s3, 0.f);
        mx = fmaxf(mx, fmaxf(fmaxf(v0, v1), fmaxf(v2, v3)));
      }
      Y[(size_t)i * ldy + l] = mx;
    } else {
      float mx = -FLT_MAX;
#pragma unroll
      for (int kb = 0; kb < KK; kb += 4) {
        float s0 = 0.f, s1 = 0.f, s2 = 0.f, s3 = 0.f;
#pragma unroll 4
        for (int j = 0; j < F; ++j) {
          f4 fv = *(const f4*)&ft[w][j * KK + kb];
          float wv = W1[j * 64 + l];
          s0 = fmaf(fv[0], wv, s0);
          s1 = fmaf(fv[1], wv, s1);
          s2 = fmaf(fv[2], wv, s2);
          s3 = fmaf(fv[3], wv, s3);
        }
        float v0 = fmaxf(s0, 0.f) + a1 * fminf(s0, 0.f);
        float v1 = fmaxf(s1, 0.f) + a1 * fminf(s1, 0.f);
        float v2 = fmaxf(s2, 0.f) + a1 * fminf(s2, 0.f);
        float v3 = fmaxf(s3, 0.f) + a1 * fminf(s3, 0.f);
        mx = fmaxf(mx, fmaxf(fmaxf(v0, v1), fmaxf(v2, v3)));
      }
      Y[(size_t)i * ldy + l] = mx;
    }
  }
}

// ---------------- ordered-float encode for atomicMax ----------------
__device__ __forceinline__ unsigned fenc(float f) {
  unsigned u = __float_as_uint(f);
  return (u & 0x80000000u) ? ~u : (u | 0x80000000u);
}
__device__ __forceinline__ float fdec(unsigned u) {
  return (u & 0x80000000u) ? __uint_as_float(u & 0x7fffffffu) : __uint_as_float(~u);
}

__global__ void initg_kernel(unsigned* __restrict__ g) {
  g[blockIdx.x * 256 + threadIdx.x] = 0x007FFFFFu;  // fenc(-inf)
}

// ---------------- generic fp32 GEMM + prelu; MODE: 0 store, 1 colmax, 2 bias+store ----
template<int MODE>
__global__ __launch_bounds__(256, 2)
void gemm_kernel(const float* __restrict__ A, int lda,
                 const float* __restrict__ W, int ldw,
                 const float* __restrict__ bias,
                 const float* __restrict__ pptr,
                 float* __restrict__ Cm, int ldc, int Ktot,
                 unsigned* __restrict__ gmax) {
  __shared__ __align__(16) float At[16 * 132];
  __shared__ __align__(16) float Ws[16 * 128];
  const int t = threadIdx.x;
  const int rb = blockIdx.x * 128, cbb = blockIdx.y * 128;
  const int r0 = (t & 15) * 8, c0 = (t >> 4) * 8;
  const float aa = *pptr;

  float acc[8][8];
#pragma unroll
  for (int i = 0; i < 8; ++i)
#pragma unroll
    for (int j = 0; j < 8; ++j) acc[i][j] = 0.f;

  const int sr = t >> 1, skh = (t & 1) * 8;
  const int wk = t >> 4, wc = (t & 15) * 8;

  for (int k0 = 0; k0 < Ktot; k0 += 16) {
    __syncthreads();
    {
      const float* ap = &A[(size_t)(rb + sr) * lda + k0 + skh];
      f4 v0 = *(const f4*)ap;
      f4 v1 = *(const f4*)(ap + 4);
#pragma unroll
      for (int e = 0; e < 4; ++e) {
        At[(skh + e) * 132 + sr] = v0[e];
        At[(skh + 4 + e) * 132 + sr] = v1[e];
      }
      const float* wp = &W[(size_t)(k0 + wk) * ldw + cbb + wc];
      *(f4*)&Ws[wk * 128 + wc] = *(const f4*)wp;
      *(f4*)&Ws[wk * 128 + wc + 4] = *(const f4*)(wp + 4);
    }
    __syncthreads();
#pragma unroll 4
    for (int d = 0; d < 16; ++d) {
      f4 qa = *(const f4*)&At[d * 132 + r0];
      f4 qb = *(const f4*)&At[d * 132 + r0 + 4];
      f4 wa = *(const f4*)&Ws[d * 128 + c0];
      f4 wb = *(const f4*)&Ws[d * 128 + c0 + 4];
      float qr[8] = {qa[0], qa[1], qa[2], qa[3], qb[0], qb[1], qb[2], qb[3]};
      float wr[8] = {wa[0], wa[1], wa[2], wa[3], wb[0], wb[1], wb[2], wb[3]};
#pragma unroll
      for (int i = 0; i < 8; ++i)
#pragma unroll
        for (int j = 0; j < 8; ++j)
          acc[i][j] = fmaf(qr[i], wr[j], acc[i][j]);
    }
  }

  float bv[8];
#pragma unroll
  for (int j = 0; j < 8; ++j) bv[j] = (MODE == 2) ? bias[cbb + c0 + j] : 0.f;
#pragma unroll
  for (int i = 0; i < 8; ++i)
#pragma unroll
    for (int j = 0; j < 8; ++j) {
      float v = acc[i][j] + bv[j];
      acc[i][j] = fmaxf(v, 0.f) + aa * fminf(v, 0.f);
    }

  if (MODE == 1) {
    float cmax[8];
#pragma unroll
    for (int j = 0; j < 8; ++j) {
      cmax[j] = acc[0][j];
#pragma unroll
      for (int i = 1; i < 8; ++i) cmax[j] = fmaxf(cmax[j], acc[i][j]);
    }
    __syncthreads();
#pragma unroll
    for (int j = 0; j < 8; ++j) At[(t & 15) * 132 + c0 + j] = cmax[j];
    __syncthreads();
    if (t < 128) {
      float m = At[t];
      for (int rr = 1; rr < 16; ++rr) m = fmaxf(m, At[rr * 132 + t]);
      atomicMax(&gmax[cbb + t], fenc(m));
    }
  } else {
#pragma unroll
    for (int i = 0; i < 8; ++i) {
      f4 s0 = {acc[i][0], acc[i][1], acc[i][2], acc[i][3]};
      f4 s1 = {acc[i][4], acc[i][5], acc[i][6], acc[i][7]};
      float* cp = &Cm[(size_t)(rb + r0 + i) * ldc + cbb + c0];
      *(f4*)cp = s0;
      *(f4*)(cp + 4) = s1;
    }
  }
}

// ---------------- bias5[c] = sum_j g[j] * W5[192+j][c] ----------------
__global__ void bias5_kernel(const unsigned* __restrict__ gmax, const float* __restrict__ W5,
                             float* __restrict__ bias5) {
  __shared__ float gs[1024];
  __shared__ float pm[4 * 256];
  int t = threadIdx.x;  // 1024 threads
  gs[t] = fdec(gmax[t]);
  __syncthreads();
  int c = t & 255, p = t >> 8;
  float acc = 0.f;
  for (int j = p * 256; j < p * 256 + 256; ++j)
    acc = fmaf(gs[j], W5[(size_t)(192 + j) * 256 + c], acc);
  pm[p * 256 + c] = acc;
  __syncthreads();
  if (t < 256) bias5[t] = pm[t] + pm[256 + t] + pm[512 + t] + pm[768 + t];
}

// ---------------- final [N,128]@[128,3] + prelu + hidden passthrough ----------------
__global__ __launch_bounds__(256, 2)
void w8_kernel(const float* __restrict__ A, const float* __restrict__ W8,
               const float* __restrict__ pptr, const float* __restrict__ hidden,
               float* __restrict__ out) {
  __shared__ __align__(16) float As[64 * 132];
  __shared__ float W8s[128 * COUT];
  int t = threadIdx.x;
  int rb = blockIdx.x * 64;
  for (int idx = t; idx < 128 * COUT; idx += 256) W8s[idx] = W8[idx];
  for (int idx = t; idx < 64 * 32; idx += 256) {
    int r = idx >> 5, c4 = idx & 31;
    *(f4*)&As[r * 132 + c4 * 4] = *(const f4*)&A[(size_t)(rb + r) * 128 + c4 * 4];
  }
  const float a = *pptr;
  __syncthreads();
  int r = t >> 2, c = t & 3;
  if (c < COUT) {
    float acc = 0.f;
#pragma unroll 8
    for (int j = 0; j < 128; ++j)
      acc = fmaf(As[r * 132 + j], W8s[j * COUT + c], acc);
    float v = fmaxf(acc, 0.f) + a * fminf(acc, 0.f);
    out[(size_t)(rb + r) * COUT + c] = v;
  }
  if (blockIdx.x == 0 && t == 0) out[(size_t)NPTS * COUT] = hidden[0];
}

// ---------------- host launch ----------------
extern "C" void kernel_launch(void* const* d_in, const int* in_sizes, int n_in,
                              void* d_out, int out_size, void* d_ws, size_t ws_size,
                              hipStream_t stream) {
  (void)in_sizes; (void)n_in; (void)out_size; (void)ws_size;
  const float* x      = (const float*)d_in[0];
  const float* hidden = (const float*)d_in[1];
  const float* W1a = (const float*)d_in[2];
  const float* p1a = (const float*)d_in[3];
  const float* W1b = (const float*)d_in[4];
  const float* p1b = (const float*)d_in[5];
  const float* W2a = (const float*)d_in[6];
  const float* p2a = (const float*)d_in[7];
  const float* W2b = (const float*)d_in[8];
  const float* p2b = (const float*)d_in[9];
  const float* W3  = (const float*)d_in[10];
  const float* p3  = (const float*)d_in[11];
  const float* W4  = (const float*)d_in[12];
  const float* p4  = (const float*)d_in[13];
  const float* W5  = (const float*)d_in[14];
  const float* p5  = (const float*)d_in[15];
  const float* W6  = (const float*)d_in[16];
  const float* p6  = (const float*)d_in[17];
  const float* W7  = (const float*)d_in[18];
  const float* p7  = (const float*)d_in[19];
  const float* W8  = (const float*)d_in[20];
  const float* p8  = (const float*)d_in[21];
  float* out = (float*)d_out;

  char* ws = (char*)d_ws;
  size_t off = 0;
  auto carve = [&](size_t bytes) -> void* {
    void* p = ws + off;
    off = (off + bytes + 255) & ~(size_t)255;
    return p;
  };
  float*    x4    = (float*)   carve((size_t)NPTS * 192 * 4);  // [x1|x2|x3], ld=192 (reused as h7)
  float*    vn    = (float*)   carve((size_t)NPTS * 4);
  int*      ind   = (int*)     carve((size_t)NPTS * KK * 4);
  float*    T     = (float*)   carve((size_t)NPTS * 4);
  unsigned* cnt   = (unsigned*)carve((size_t)NPTS * 4);
  unsigned* gmax  = (unsigned*)carve(1024 * 4);
  float*    bias5 = (float*)   carve(256 * 4);
  float*    h5    = (float*)   carve((size_t)NPTS * 256 * 4);  // aliased: survd (knn phase)
  float*    h6    = (float*)   carve((size_t)NPTS * 256 * 4);  // aliased: survi (knn phase)
  float* survd = h5;
  int*   survi = (int*)h6;
  float* h7 = x4;  // x4 dead after W5 GEMM

  // ---- stage 1: knn(x, C=3) + edgeconv1 -> x4[:, 0:64] ----
  norms_kernel<3><<<64, 256, 0, stream>>>(x, 3, vn);
  sampleT_kernel<3><<<2048, 256, 0, stream>>>(x, 3, vn, T, cnt);
  knn_filter_kernel<3><<<dim3(128, 8), 256, 0, stream>>>(x, 3, vn, T, survd, survi, cnt);
  select_kernel<3><<<64, 256, 0, stream>>>(x, 3, vn, survd, survi, cnt, ind);
  edgeconv_kernel<3, true><<<512, 256, 0, stream>>>(x, 3, ind, W1a, p1a, W1b, p1b, x4 + 0, 192);

  // ---- stage 2: knn(x1) + edgeconv2 -> x4[:, 64:128] ----
  norms_kernel<64><<<64, 256, 0, stream>>>(x4 + 0, 192, vn);
  sampleT_kernel<64><<<2048, 256, 0, stream>>>(x4 + 0, 192, vn, T, cnt);
  knn_filter_kernel<64><<<dim3(128, 8), 256, 0, stream>>>(x4 + 0, 192, vn, T, survd, survi, cnt);
  select_kernel<64><<<64, 256, 0, stream>>>(x4 + 0, 192, vn, survd, survi, cnt, ind);
  edgeconv_kernel<64, true><<<512, 256, 0, stream>>>(x4 + 0, 192, ind, W2a, p2a, W2b, p2b, x4 + 64, 192);

  // ---- stage 3: knn(x2) + edgeconv3 -> x4[:, 128:192] ----
  norms_kernel<64><<<64, 256, 0, stream>>>(x4 + 64, 192, vn);
  sampleT_kernel<64><<<2048, 256, 0, stream>>>(x4 + 64, 192, vn, T, cnt);
  knn_filter_kernel<64><<<dim3(128, 8), 256, 0, stream>>>(x4 + 64, 192, vn, T, survd, survi, cnt);
  select_kernel<64><<<64, 256, 0, stream>>>(x4 + 64, 192, vn, survd, survi, cnt, ind);
  edgeconv_kernel<64, false><<<512, 256, 0, stream>>>(x4 + 64, 192, ind, W3, p3, nullptr, nullptr, x4 + 128, 192);

  // ---- x5 = prelu(x4@W4); g = colmax(x5) ----
  initg_kernel<<<4, 256, 0, stream>>>(gmax);
  gemm_kernel<1><<<dim3(128, 8), 256, 0, stream>>>(x4, 192, W4, 1024, nullptr, p4, nullptr, 0, 192, gmax);

  // ---- bias5 = g @ W5[192:1216] ----
  bias5_kernel<<<1, 1024, 0, stream>>>(gmax, W5, bias5);

  // ---- h5 = prelu(x4@W5[0:192] + bias5) ----
  gemm_kernel<2><<<dim3(128, 2), 256, 0, stream>>>(x4, 192, W5, 256, bias5, p5, h5, 256, 192, nullptr);
  // ---- h6 = prelu(h5@W6) ----
  gemm_kernel<0><<<dim3(128, 2), 256, 0, stream>>>(h5, 256, W6, 256, nullptr, p6, h6, 256, 256, nullptr);
  // ---- h7 = prelu(h6@W7) ----
  gemm_kernel<0><<<dim3(128, 1), 256, 0, stream>>>(h6, 256, W7, 128, nullptr, p7, h7, 128, 256, nullptr);
  // ---- out = prelu(h7@W8); out[N*3] = hidden ----
  w8_kernel<<<256, 256, 0, stream>>>(h7, W8, p8, hidden, out);
}

// Round 6
// 4161.234 us; speedup vs baseline: 5.0701x; 1.1988x over previous
//
#include <hip/hip_runtime.h>
#include <hip/hip_bf16.h>
#include <float.h>

#define NPTS 16384
#define KK 20
#define COUT 3
#define SURV_CAP 256

typedef float f4 __attribute__((ext_vector_type(4)));

// ---------------- sorted top-20 insert, values only ----------------
__device__ __forceinline__ void ins20(float (&td)[KK], float &kmax, float nd) {
  float cd = nd;
#pragma unroll
  for (int j = 0; j < KK; ++j) {
    float t0 = td[j];
    bool lt = cd < t0;
    td[j] = lt ? cd : t0;
    cd = lt ? t0 : cd;
  }
  kmax = td[KK - 1];
}

// ---------------- sorted top-20 insert, (value, index) ----------------
__device__ __forceinline__ void ins20p(float (&td)[KK], int (&ti)[KK],
                                       float &kmax, float nd, int ni) {
  float cd = nd; int ci = ni;
#pragma unroll
  for (int j = 0; j < KK; ++j) {
    float t0 = td[j]; int t1 = ti[j];
    bool lt = cd < t0;
    td[j] = lt ? cd : t0;  ti[j] = lt ? ci : t1;
    cd = lt ? t0 : cd;     ci = lt ? t1 : ci;
  }
  kmax = td[KK - 1];
}

// ---------------- row squared norms ----------------
template<int C>
__global__ void norms_kernel(const float* __restrict__ X, int ldx, float* __restrict__ vn) {
  int i = blockIdx.x * 256 + threadIdx.x;
  if (i >= NPTS) return;
  const float* row = X + (size_t)i * ldx;
  float s = 0.f;
#pragma unroll
  for (int c = 0; c < C; ++c) s = fmaf(row[c], row[c], s);
  vn[i] = s;
}

// ---------------- phase S (v3): per-query threshold from stride-6 sample ----------
// Block = 8 query-groups x 32 lanes; query held in REGISTERS; candidates staged in
// LDS slot-major with XOR swizzle, read as f4 (16 ds_read_b128 per candidate instead
// of 128 scalar reads). m = 2688 (21 chunks of 128). Also zeroes cnt[q], redoCnt.
template<int C>
__global__ __launch_bounds__(256, 2)
void sampleT_kernel(const float* __restrict__ X, int ldx, const float* __restrict__ vn,
                    float* __restrict__ T, unsigned* __restrict__ cnt,
                    unsigned* __restrict__ redoCnt) {
  constexpr int GQ = 8, GL = 32;
  constexpr int CHUNK = 128;
  constexpr int NCHK = 21;          // m = 2688
  constexpr int STRIDE = 6;         // 2688*6 = 16128 < 16384
  constexpr int CPL = CHUNK / GL;   // 4 candidates per lane per chunk
  __shared__ float mrg[GQ][GL * KK];            // 20 KB
  __shared__ float cn[CHUNK];

  const int t = threadIdx.x;
  const int g = t >> 5, l = t & 31;
  const int q = blockIdx.x * GQ + g;

  if (blockIdx.x == 0 && t == 0) *redoCnt = 0u;

  float td[KK];
#pragma unroll
  for (int j = 0; j < KK; ++j) td[j] = FLT_MAX;
  float kmax = FLT_MAX;

  if constexpr (C >= 32) {
    constexpr int NS = C / 4;                    // 16 f4 slots
    __shared__ __align__(16) f4 Cs4[NS * CHUNK]; // 32 KB, layout [s][r ^ (s&7)]
    f4 qreg[NS];
#pragma unroll
    for (int s = 0; s < NS; ++s)
      qreg[s] = *(const f4*)&X[(size_t)q * ldx + s * 4];

    for (int ck = 0; ck < NCHK; ++ck) {
      __syncthreads();  // prior chunk consumed
      for (int idx = t; idx < NS * CHUNK; idx += 256) {
        int r = idx >> 4, s = idx & (NS - 1);    // consecutive t -> slots of same row (coalesced)
        int c = (ck * CHUNK + r) * STRIDE;
        Cs4[s * CHUNK + (r ^ (s & 7))] = *(const f4*)&X[(size_t)c * ldx + s * 4];
      }
      if (t < CHUNK) cn[t] = vn[(ck * CHUNK + t) * STRIDE];
      __syncthreads();
#pragma unroll
      for (int u = 0; u < CPL; ++u) {
        const int r = u * GL + l;
        float d0 = 0.f, d1 = 0.f, d2 = 0.f, d3 = 0.f;
#pragma unroll
        for (int s = 0; s < NS; ++s) {
          f4 cv = Cs4[s * CHUNK + (r ^ (s & 7))];
          d0 = fmaf(cv[0], qreg[s][0], d0);
          d1 = fmaf(cv[1], qreg[s][1], d1);
          d2 = fmaf(cv[2], qreg[s][2], d2);
          d3 = fmaf(cv[3], qreg[s][3], d3);
        }
        float sv = fmaf(-2.f, (d0 + d1) + (d2 + d3), cn[r]);
        if (sv < kmax) ins20(td, kmax, sv);
      }
    }
  } else {
    __shared__ float Cs[CHUNK * C];
    float qreg[C];
#pragma unroll
    for (int d = 0; d < C; ++d) qreg[d] = X[(size_t)q * ldx + d];

    for (int ck = 0; ck < NCHK; ++ck) {
      __syncthreads();
      for (int idx = t; idx < CHUNK * C; idx += 256) {
        int r = idx / C, d = idx - r * C;
        Cs[r * C + d] = X[(size_t)((ck * CHUNK + r) * STRIDE) * ldx + d];
      }
      if (t < CHUNK) cn[t] = vn[(ck * CHUNK + t) * STRIDE];
      __syncthreads();
#pragma unroll
      for (int u = 0; u < CPL; ++u) {
        const int r = u * GL + l;
        const float* crow = &Cs[r * C];
        float d0 = 0.f;
#pragma unroll
        for (int d = 0; d < C; ++d) d0 = fmaf(crow[d], qreg[d], d0);
        float sv = fmaf(-2.f, d0, cn[r]);
        if (sv < kmax) ins20(td, kmax, sv);
      }
    }
  }

#pragma unroll
  for (int j = 0; j < KK; ++j) mrg[g][l * KK + j] = td[j];
  __syncthreads();
  if (l == 0) {
    float md[KK];
#pragma unroll
    for (int j = 0; j < KK; ++j) md[j] = FLT_MAX;
    float km = FLT_MAX;
    for (int ll = 0; ll < GL; ++ll) {
      for (int j = 0; j < KK; ++j) {
        float v = mrg[g][ll * KK + j];
        if (v < km) ins20(md, km, v);
        else break;  // per-lane lists sorted ascending
      }
    }
    // pad covers dot-reassociation ulps between sample (4-chain) and filter (1-chain)
    T[q] = md[KK - 1] + 1e-4f * (fabsf(md[KK - 1]) + 1.0f);
    cnt[q] = 0u;
  }
}

// ---------------- phase F: tiled distance GEMM + threshold filter -> survivors ----
// grid (128, 8) x 256. Per block: 128 queries x 2048 candidates (16 tiles).
template<int C>
__global__ __launch_bounds__(256, 4)
void knn_filter_kernel(const float* __restrict__ X, int ldx, const float* __restrict__ vn,
                       const float* __restrict__ T,
                       float* __restrict__ survd, int* __restrict__ survi,
                       unsigned* __restrict__ cnt) {
  constexpr int QT = 128, CT = 128, CSTR = CT + 4;
  constexpr int KC = (C < 32) ? C : 32;
  constexpr int NCH = (C + KC - 1) / KC;
  __shared__ __align__(16) float Qs[KC * QT];
  __shared__ __align__(16) float Cs[KC * CSTR];
  __shared__ float cnorm[CT];
  __shared__ float Tsl[QT];

  const int t = threadIdx.x;
  const int qb = blockIdx.x * QT;
  const int cbase = blockIdx.y * (NPTS / 8);

  if (t < QT) Tsl[t] = T[qb + t];

  const int tq = t & 15, tc = t >> 4;
  const int q0 = tq * 8, c0 = tc * 8;

  for (int ct = 0; ct < (NPTS / 8) / CT; ++ct) {
    const int cb = cbase + ct * CT;

    float acc[8][8];
#pragma unroll
    for (int i = 0; i < 8; ++i)
#pragma unroll
      for (int j = 0; j < 8; ++j) acc[i][j] = 0.f;

    for (int kc = 0; kc < NCH; ++kc) {
      __syncthreads();  // prior tile finalize / Tsl load done
      for (int idx = t; idx < KC * QT; idx += 256) {
        int q = idx / KC, c = idx - q * KC;
        Qs[c * QT + q] = X[(size_t)(qb + q) * ldx + kc * KC + c];
      }
      for (int idx = t; idx < KC * CT; idx += 256) {
        int j = idx / KC, c = idx - j * KC;
        Cs[c * CSTR + j] = X[(size_t)(cb + j) * ldx + kc * KC + c];
      }
      if (kc == 0 && t < CT) cnorm[t] = vn[cb + t];
      __syncthreads();

#pragma unroll 2
      for (int d = 0; d < KC; ++d) {
        f4 qa = *(const f4*)&Qs[d * QT + q0];
        f4 qbv = *(const f4*)&Qs[d * QT + q0 + 4];
        f4 ca = *(const f4*)&Cs[d * CSTR + c0];
        f4 cbv = *(const f4*)&Cs[d * CSTR + c0 + 4];
        float qr[8] = {qa[0], qa[1], qa[2], qa[3], qbv[0], qbv[1], qbv[2], qbv[3]};
        float cr[8] = {ca[0], ca[1], ca[2], ca[3], cbv[0], cbv[1], cbv[2], cbv[3]};
#pragma unroll
        for (int i = 0; i < 8; ++i)
#pragma unroll
          for (int j = 0; j < 8; ++j)
            acc[i][j] = fmaf(qr[i], cr[j], acc[i][j]);
      }
    }

    // s = vn_c - 2<q,c>; append survivors s <= T[q]
#pragma unroll
    for (int j = 0; j < 8; ++j) {
      float cv = cnorm[c0 + j];
#pragma unroll
      for (int i = 0; i < 8; ++i)
        acc[i][j] = fmaf(-2.f, acc[i][j], cv);
    }
#pragma unroll
    for (int i = 0; i < 8; ++i) {
      const float tcut = Tsl[q0 + i];
      const int q = qb + q0 + i;
#pragma unroll
      for (int j = 0; j < 8; ++j) {
        if (acc[i][j] <= tcut) {
          unsigned p = atomicAdd(&cnt[q], 1u);
          if (p < SURV_CAP) {
            survd[(size_t)q * SURV_CAP + p] = acc[i][j];
            survi[(size_t)q * SURV_CAP + p] = cb + c0 + j;
          }
        }
      }
    }
  }
}

// ---------------- phase Sel: exact top-20 among survivors (overflow -> redo list) --
__global__ __launch_bounds__(256, 2)
void select_kernel(const float* __restrict__ survd, const int* __restrict__ survi,
                   const unsigned* __restrict__ cnt, int* __restrict__ ind,
                   unsigned* __restrict__ redoCnt, int* __restrict__ redoList) {
  const int q = blockIdx.x * 256 + threadIdx.x;
  const unsigned n = cnt[q];
  if (n > SURV_CAP) {   // rare (P ~ 5e-7/query): defer to exact redo kernel
    unsigned p = atomicAdd(redoCnt, 1u);
    redoList[p] = q;
    return;
  }
  float td[KK]; int ti[KK];
#pragma unroll
  for (int j = 0; j < KK; ++j) { td[j] = FLT_MAX; ti[j] = 0; }
  float kmax = FLT_MAX;
  for (unsigned i = 0; i < n; ++i) {
    float d = survd[(size_t)q * SURV_CAP + i];
    if (d < kmax) ins20p(td, ti, kmax, d, survi[(size_t)q * SURV_CAP + i]);
  }
#pragma unroll
  for (int j = 0; j < KK; ++j) ind[q * KK + j] = ti[j];
}

// ---------------- redo: exact parallel top-20 full scan for overflowed queries ----
template<int C>
__global__ __launch_bounds__(256, 2)
void knn_redo_kernel(const float* __restrict__ X, int ldx, const float* __restrict__ vn,
                     const int* __restrict__ redoList, const unsigned* __restrict__ redoCnt,
                     int* __restrict__ ind) {
  __shared__ float lds_d[256 * KK];   // 20 KB
  __shared__ int   lds_i[256 * KK];   // 20 KB
  const int t = threadIdx.x;
  const unsigned n = *redoCnt;
  for (unsigned e = blockIdx.x; e < n; e += gridDim.x) {
    const int q = redoList[e];
    float qreg[C];
#pragma unroll
    for (int d = 0; d < C; ++d) qreg[d] = X[(size_t)q * ldx + d];
    float td[KK]; int ti[KK];
#pragma unroll
    for (int j = 0; j < KK; ++j) { td[j] = FLT_MAX; ti[j] = 0; }
    float kmax = FLT_MAX;
    for (int c = t; c < NPTS; c += 256) {
      const float* crow = X + (size_t)c * ldx;
      float d0 = 0.f;
#pragma unroll 4
      for (int d = 0; d < C; ++d) d0 = fmaf(crow[d], qreg[d], d0);
      float sv = fmaf(-2.f, d0, vn[c]);
      if (sv < kmax) ins20p(td, ti, kmax, sv, c);
    }
#pragma unroll
    for (int j = 0; j < KK; ++j) { lds_d[t * KK + j] = td[j]; lds_i[t * KK + j] = ti[j]; }
    __syncthreads();
    if (t == 0) {
      float md[KK]; int mi[KK];
#pragma unroll
      for (int j = 0; j < KK; ++j) { md[j] = FLT_MAX; mi[j] = 0; }
      float km = FLT_MAX;
      for (int ll = 0; ll < 256; ++ll) {
        for (int j = 0; j < KK; ++j) {
          float v = lds_d[ll * KK + j];
          if (v < km) ins20p(md, mi, km, v, lds_i[ll * KK + j]);
          else break;
        }
      }
#pragma unroll
      for (int j = 0; j < KK; ++j) ind[q * KK + j] = mi[j];
    }
    __syncthreads();
  }
}

// ---------------- edge conv: gather + (f@W1 prelu [@W2 prelu]) + max over k ----------
template<int CIN, bool TWO>
__global__ __launch_bounds__(256, 2)
void edgeconv_kernel(const float* __restrict__ X, int ldx,
                     const int* __restrict__ ind,
                     const float* __restrict__ W1, const float* __restrict__ p1p,
                     const float* __restrict__ W2, const float* __restrict__ p2p,
                     float* __restrict__ Y, int ldy) {
  constexpr int F = 2 * CIN;
  __shared__ __align__(16) float ft[4][F * KK];
  __shared__ __align__(16) float h1t[4][TWO ? 64 * KK : 4];
  __shared__ float xis[4][CIN];
  __shared__ int nbs[4][KK];

  const int t = threadIdx.x;
  const int w = t >> 6, l = t & 63;
  const float a1 = *p1p;
  float a2 = 0.f;
  if constexpr (TWO) a2 = *p2p;

  for (int pp = 0; pp < 8; ++pp) {
    const int i = blockIdx.x * 32 + w * 8 + pp;
    __syncthreads();
    if (l < CIN) xis[w][l] = X[(size_t)i * ldx + l];
    if (l < KK) nbs[w][l] = ind[i * KK + l];
    __syncthreads();
    for (int idx = l; idx < F * KK; idx += 64) {
      int j = idx / KK, k = idx - j * KK;
      float v;
      if (j < CIN) v = X[(size_t)nbs[w][k] * ldx + j] - xis[w][j];
      else v = xis[w][j - CIN];
      ft[w][idx] = v;
    }
    __syncthreads();

    if constexpr (TWO) {
#pragma unroll
      for (int kb = 0; kb < KK; kb += 4) {
        float s0 = 0.f, s1 = 0.f, s2 = 0.f, s3 = 0.f;
#pragma unroll 4
        for (int j = 0; j < F; ++j) {
          f4 fv = *(const f4*)&ft[w][j * KK + kb];
          float wv = W1[j * 64 + l];
          s0 = fmaf(fv[0], wv, s0);
          s1 = fmaf(fv[1], wv, s1);
          s2 = fmaf(fv[2], wv, s2);
          s3 = fmaf(fv[3], wv, s3);
        }
        f4 h;
        h[0] = fmaxf(s0, 0.f) + a1 * fminf(s0, 0.f);
        h[1] = fmaxf(s1, 0.f) + a1 * fminf(s1, 0.f);
        h[2] = fmaxf(s2, 0.f) + a1 * fminf(s2, 0.f);
        h[3] = fmaxf(s3, 0.f) + a1 * fminf(s3, 0.f);
        *(f4*)&h1t[w][l * KK + kb] = h;
      }
      __syncthreads();
      float mx = -FLT_MAX;
#pragma unroll
      for (int kb = 0; kb < KK; kb += 4) {
        float s0 = 0.f, s1 = 0.f, s2 = 0.f, s3 = 0.f;
#pragma unroll 4
        for (int j = 0; j < 64; ++j) {
          f4 hv = *(const f4*)&h1t[w][j * KK + kb];
          float wv = W2[j * 64 + l];
          s0 = fmaf(hv[0], wv, s0);
          s1 = fmaf(hv[1], wv, s1);
          s2 = fmaf(hv[2], wv, s2);
          s3 = fmaf(hv[3], wv, s3);
        }
        float v0 = fmaxf(s0, 0.f) + a2 * fminf(s0, 0.f);
        float v1 = fmaxf(s1, 0.f) + a2 * fminf(s1, 0.f);
        float v2 = fmaxf(s2, 0.f) + a2 * fminf(s2, 0.f);
        float v3 = fmaxf(s3, 0.f) + a2 * fminf(s3, 0.f);
        mx = fmaxf(mx, fmaxf(fmaxf(v0, v1), fmaxf(v2, v3)));
      }
      Y[(size_t)i * ldy + l] = mx;
    } else {
      float mx = -FLT_MAX;
#pragma unroll
      for (int kb = 0; kb < KK; kb += 4) {
        float s0 = 0.f, s1 = 0.f, s2 = 0.f, s3 = 0.f;
#pragma unroll 4
        for (int j = 0; j < F; ++j) {
          f4 fv = *(const f4*)&ft[w][j * KK + kb];
          float wv = W1[j * 64 + l];
          s0 = fmaf(fv[0], wv, s0);
          s1 = fmaf(fv[1], wv, s1);
          s2 = fmaf(fv[2], wv, s2);
          s3 = fmaf(fv[3], wv, s3);
        }
        float v0 = fmaxf(s0, 0.f) + a1 * fminf(s0, 0.f);
        float v1 = fmaxf(s1, 0.f) + a1 * fminf(s1, 0.f);
        float v2 = fmaxf(s2, 0.f) + a1 * fminf(s2, 0.f);
        float v3 = fmaxf(s3, 0.f) + a1 * fminf(s3, 0.f);
        mx = fmaxf(mx, fmaxf(fmaxf(v0, v1), fmaxf(v2, v3)));
      }
      Y[(size_t)i * ldy + l] = mx;
    }
  }
}

// ---------------- ordered-float encode for atomicMax ----------------
__device__ __forceinline__ unsigned fenc(float f) {
  unsigned u = __float_as_uint(f);
  return (u & 0x80000000u) ? ~u : (u | 0x80000000u);
}
__device__ __forceinline__ float fdec(unsigned u) {
  return (u & 0x80000000u) ? __uint_as_float(u & 0x7fffffffu) : __uint_as_float(~u);
}

__global__ void initg_kernel(unsigned* __restrict__ g) {
  g[blockIdx.x * 256 + threadIdx.x] = 0x007FFFFFu;  // fenc(-inf)
}

// ---------------- generic fp32 GEMM + prelu; MODE: 0 store, 1 colmax, 2 bias+store ----
template<int MODE>
__global__ __launch_bounds__(256, 2)
void gemm_kernel(const float* __restrict__ A, int lda,
                 const float* __restrict__ W, int ldw,
                 const float* __restrict__ bias,
                 const float* __restrict__ pptr,
                 float* __restrict__ Cm, int ldc, int Ktot,
                 unsigned* __restrict__ gmax) {
  __shared__ __align__(16) float At[16 * 132];
  __shared__ __align__(16) float Ws[16 * 128];
  const int t = threadIdx.x;
  const int rb = blockIdx.x * 128, cbb = blockIdx.y * 128;
  const int r0 = (t & 15) * 8, c0 = (t >> 4) * 8;
  const float aa = *pptr;

  float acc[8][8];
#pragma unroll
  for (int i = 0; i < 8; ++i)
#pragma unroll
    for (int j = 0; j < 8; ++j) acc[i][j] = 0.f;

  const int sr = t >> 1, skh = (t & 1) * 8;
  const int wk = t >> 4, wc = (t & 15) * 8;

  for (int k0 = 0; k0 < Ktot; k0 += 16) {
    __syncthreads();
    {
      const float* ap = &A[(size_t)(rb + sr) * lda + k0 + skh];
      f4 v0 = *(const f4*)ap;
      f4 v1 = *(const f4*)(ap + 4);
#pragma unroll
      for (int e = 0; e < 4; ++e) {
        At[(skh + e) * 132 + sr] = v0[e];
        At[(skh + 4 + e) * 132 + sr] = v1[e];
      }
      const float* wp = &W[(size_t)(k0 + wk) * ldw + cbb + wc];
      *(f4*)&Ws[wk * 128 + wc] = *(const f4*)wp;
      *(f4*)&Ws[wk * 128 + wc + 4] = *(const f4*)(wp + 4);
    }
    __syncthreads();
#pragma unroll 4
    for (int d = 0; d < 16; ++d) {
      f4 qa = *(const f4*)&At[d * 132 + r0];
      f4 qb = *(const f4*)&At[d * 132 + r0 + 4];
      f4 wa = *(const f4*)&Ws[d * 128 + c0];
      f4 wb = *(const f4*)&Ws[d * 128 + c0 + 4];
      float qr[8] = {qa[0], qa[1], qa[2], qa[3], qb[0], qb[1], qb[2], qb[3]};
      float wr[8] = {wa[0], wa[1], wa[2], wa[3], wb[0], wb[1], wb[2], wb[3]};
#pragma unroll
      for (int i = 0; i < 8; ++i)
#pragma unroll
        for (int j = 0; j < 8; ++j)
          acc[i][j] = fmaf(qr[i], wr[j], acc[i][j]);
    }
  }

  float bv[8];
#pragma unroll
  for (int j = 0; j < 8; ++j) bv[j] = (MODE == 2) ? bias[cbb + c0 + j] : 0.f;
#pragma unroll
  for (int i = 0; i < 8; ++i)
#pragma unroll
    for (int j = 0; j < 8; ++j) {
      float v = acc[i][j] + bv[j];
      acc[i][j] = fmaxf(v, 0.f) + aa * fminf(v, 0.f);
    }

  if (MODE == 1) {
    float cmax[8];
#pragma unroll
    for (int j = 0; j < 8; ++j) {
      cmax[j] = acc[0][j];
#pragma unroll
      for (int i = 1; i < 8; ++i) cmax[j] = fmaxf(cmax[j], acc[i][j]);
    }
    __syncthreads();
#pragma unroll
    for (int j = 0; j < 8; ++j) At[(t & 15) * 132 + c0 + j] = cmax[j];
    __syncthreads();
    if (t < 128) {
      float m = At[t];
      for (int rr = 1; rr < 16; ++rr) m = fmaxf(m, At[rr * 132 + t]);
      atomicMax(&gmax[cbb + t], fenc(m));
    }
  } else {
#pragma unroll
    for (int i = 0; i < 8; ++i) {
      f4 s0 = {acc[i][0], acc[i][1], acc[i][2], acc[i][3]};
      f4 s1 = {acc[i][4], acc[i][5], acc[i][6], acc[i][7]};
      float* cp = &Cm[(size_t)(rb + r0 + i) * ldc + cbb + c0];
      *(f4*)cp = s0;
      *(f4*)(cp + 4) = s1;
    }
  }
}

// ---------------- bias5[c] = sum_j g[j] * W5[192+j][c] ----------------
__global__ void bias5_kernel(const unsigned* __restrict__ gmax, const float* __restrict__ W5,
                             float* __restrict__ bias5) {
  __shared__ float gs[1024];
  __shared__ float pm[4 * 256];
  int t = threadIdx.x;  // 1024 threads
  gs[t] = fdec(gmax[t]);
  __syncthreads();
  int c = t & 255, p = t >> 8;
  float acc = 0.f;
  for (int j = p * 256; j < p * 256 + 256; ++j)
    acc = fmaf(gs[j], W5[(size_t)(192 + j) * 256 + c], acc);
  pm[p * 256 + c] = acc;
  __syncthreads();
  if (t < 256) bias5[t] = pm[t] + pm[256 + t] + pm[512 + t] + pm[768 + t];
}

// ---------------- final [N,128]@[128,3] + prelu + hidden passthrough ----------------
__global__ __launch_bounds__(256, 2)
void w8_kernel(const float* __restrict__ A, const float* __restrict__ W8,
               const float* __restrict__ pptr, const float* __restrict__ hidden,
               float* __restrict__ out) {
  __shared__ __align__(16) float As[64 * 132];
  __shared__ float W8s[128 * COUT];
  int t = threadIdx.x;
  int rb = blockIdx.x * 64;
  for (int idx = t; idx < 128 * COUT; idx += 256) W8s[idx] = W8[idx];
  for (int idx = t; idx < 64 * 32; idx += 256) {
    int r = idx >> 5, c4 = idx & 31;
    *(f4*)&As[r * 132 + c4 * 4] = *(const f4*)&A[(size_t)(rb + r) * 128 + c4 * 4];
  }
  const float a = *pptr;
  __syncthreads();
  int r = t >> 2, c = t & 3;
  if (c < COUT) {
    float acc = 0.f;
#pragma unroll 8
    for (int j = 0; j < 128; ++j)
      acc = fmaf(As[r * 132 + j], W8s[j * COUT + c], acc);
    float v = fmaxf(acc, 0.f) + a * fminf(acc, 0.f);
    out[(size_t)(rb + r) * COUT + c] = v;
  }
  if (blockIdx.x == 0 && t == 0) out[(size_t)NPTS * COUT] = hidden[0];
}

// ---------------- host launch ----------------
extern "C" void kernel_launch(void* const* d_in, const int* in_sizes, int n_in,
                              void* d_out, int out_size, void* d_ws, size_t ws_size,
                              hipStream_t stream) {
  (void)in_sizes; (void)n_in; (void)out_size; (void)ws_size;
  const float* x      = (const float*)d_in[0];
  const float* hidden = (const float*)d_in[1];
  const float* W1a = (const float*)d_in[2];
  const float* p1a = (const float*)d_in[3];
  const float* W1b = (const float*)d_in[4];
  const float* p1b = (const float*)d_in[5];
  const float* W2a = (const float*)d_in[6];
  const float* p2a = (const float*)d_in[7];
  const float* W2b = (const float*)d_in[8];
  const float* p2b = (const float*)d_in[9];
  const float* W3  = (const float*)d_in[10];
  const float* p3  = (const float*)d_in[11];
  const float* W4  = (const float*)d_in[12];
  const float* p4  = (const float*)d_in[13];
  const float* W5  = (const float*)d_in[14];
  const float* p5  = (const float*)d_in[15];
  const float* W6  = (const float*)d_in[16];
  const float* p6  = (const float*)d_in[17];
  const float* W7  = (const float*)d_in[18];
  const float* p7  = (const float*)d_in[19];
  const float* W8  = (const float*)d_in[20];
  const float* p8  = (const float*)d_in[21];
  float* out = (float*)d_out;

  char* ws = (char*)d_ws;
  size_t off = 0;
  auto carve = [&](size_t bytes) -> void* {
    void* p = ws + off;
    off = (off + bytes + 255) & ~(size_t)255;
    return p;
  };
  float*    x4    = (float*)   carve((size_t)NPTS * 192 * 4);  // [x1|x2|x3], ld=192 (reused as h7)
  float*    vn    = (float*)   carve((size_t)NPTS * 4);
  int*      ind   = (int*)     carve((size_t)NPTS * KK * 4);
  float*    T     = (float*)   carve((size_t)NPTS * 4);
  unsigned* cnt   = (unsigned*)carve((size_t)NPTS * 4);
  unsigned* redoCnt = (unsigned*)carve(256);
  int*      redoList = (int*)  carve((size_t)NPTS * 4);
  unsigned* gmax  = (unsigned*)carve(1024 * 4);
  float*    bias5 = (float*)   carve(256 * 4);
  float*    h5    = (float*)   carve((size_t)NPTS * 256 * 4);  // aliased: survd (knn phase)
  float*    h6    = (float*)   carve((size_t)NPTS * 256 * 4);  // aliased: survi (knn phase)
  float* survd = h5;
  int*   survi = (int*)h6;
  float* h7 = x4;  // x4 dead after W5 GEMM

  // ---- stage 1: knn(x, C=3) + edgeconv1 -> x4[:, 0:64] ----
  norms_kernel<3><<<64, 256, 0, stream>>>(x, 3, vn);
  sampleT_kernel<3><<<2048, 256, 0, stream>>>(x, 3, vn, T, cnt, redoCnt);
  knn_filter_kernel<3><<<dim3(128, 8), 256, 0, stream>>>(x, 3, vn, T, survd, survi, cnt);
  select_kernel<<<64, 256, 0, stream>>>(survd, survi, cnt, ind, redoCnt, redoList);
  knn_redo_kernel<3><<<64, 256, 0, stream>>>(x, 3, vn, redoList, redoCnt, ind);
  edgeconv_kernel<3, true><<<512, 256, 0, stream>>>(x, 3, ind, W1a, p1a, W1b, p1b, x4 + 0, 192);

  // ---- stage 2: knn(x1) + edgeconv2 -> x4[:, 64:128] ----
  norms_kernel<64><<<64, 256, 0, stream>>>(x4 + 0, 192, vn);
  sampleT_kernel<64><<<2048, 256, 0, stream>>>(x4 + 0, 192, vn, T, cnt, redoCnt);
  knn_filter_kernel<64><<<dim3(128, 8), 256, 0, stream>>>(x4 + 0, 192, vn, T, survd, survi, cnt);
  select_kernel<<<64, 256, 0, stream>>>(survd, survi, cnt, ind, redoCnt, redoList);
  knn_redo_kernel<64><<<64, 256, 0, stream>>>(x4 + 0, 192, vn, redoList, redoCnt, ind);
  edgeconv_kernel<64, true><<<512, 256, 0, stream>>>(x4 + 0, 192, ind, W2a, p2a, W2b, p2b, x4 + 64, 192);

  // ---- stage 3: knn(x2) + edgeconv3 -> x4[:, 128:192] ----
  norms_kernel<64><<<64, 256, 0, stream>>>(x4 + 64, 192, vn);
  sampleT_kernel<64><<<2048, 256, 0, stream>>>(x4 + 64, 192, vn, T, cnt, redoCnt);
  knn_filter_kernel<64><<<dim3(128, 8), 256, 0, stream>>>(x4 + 64, 192, vn, T, survd, survi, cnt);
  select_kernel<<<64, 256, 0, stream>>>(survd, survi, cnt, ind, redoCnt, redoList);
  knn_redo_kernel<64><<<64, 256, 0, stream>>>(x4 + 64, 192, vn, redoList, redoCnt, ind);
  edgeconv_kernel<64, false><<<512, 256, 0, stream>>>(x4 + 64, 192, ind, W3, p3, nullptr, nullptr, x4 + 128, 192);

  // ---- x5 = prelu(x4@W4); g = colmax(x5) ----
  initg_kernel<<<4, 256, 0, stream>>>(gmax);
  gemm_kernel<1><<<dim3(128, 8), 256, 0, stream>>>(x4, 192, W4, 1024, nullptr, p4, nullptr, 0, 192, gmax);

  // ---- bias5 = g @ W5[192:1216] ----
  bias5_kernel<<<1, 1024, 0, stream>>>(gmax, W5, bias5);

  // ---- h5 = prelu(x4@W5[0:192] + bias5) ----
  gemm_kernel<2><<<dim3(128, 2), 256, 0, stream>>>(x4, 192, W5, 256, bias5, p5, h5, 256, 192, nullptr);
  // ---- h6 = prelu(h5@W6) ----
  gemm_kernel<0><<<dim3(128, 2), 256, 0, stream>>>(h5, 256, W6, 256, nullptr, p6, h6, 256, 256, nullptr);
  // ---- h7 = prelu(h6@W7) ----
  gemm_kernel<0><<<dim3(128, 1), 256, 0, stream>>>(h6, 256, W7, 128, nullptr, p7, h7, 128, 256, nullptr);
  // ---- out = prelu(h7@W8); out[N*3] = hidden ----
  w8_kernel<<<256, 256, 0, stream>>>(h7, W8, p8, hidden, out);
}